// Round 3
// baseline (1105.151 us; speedup 1.0000x reference)
//
#include <hip/hip_runtime.h>

typedef unsigned short u16;
typedef __bf16 bf16x8 __attribute__((ext_vector_type(8)));
typedef float f32x4 __attribute__((ext_vector_type(4)));

#define HN 128
#define TM 64
#define ASTRIDE 136   // 128 + 8 pad (u16), rows 16B-aligned
#define EGRID 768
#define ESLOTS 96     // EGRID/8

__device__ __forceinline__ u16 f2bf(float f) {
  union { float f; unsigned u; } v; v.f = f;
  unsigned r = v.u + 0x7fffu + ((v.u >> 16) & 1u);
  return (u16)(r >> 16);
}
__device__ __forceinline__ float bf2f(u16 v) {
  union { unsigned u; float f; } x; x.u = ((unsigned)v) << 16; return x.f;
}
__device__ __forceinline__ float silu_f(float x) { return x / (1.f + __expf(-x)); }

// ---- pack weights into MFMA B-fragment layout: P[kg][n][8], kg=k/8 ----
// mats per layer: 0=msgW1a 1=msgW1b 2=msgW2 3=nodeW1a 4=nodeW1b 5=nodeW2
// tail region: per-layer w1d (dist column of msg_w1) as bf16 [4][128]
__global__ void pack_weights(const float* __restrict__ msg_w1, const float* __restrict__ msg_w2,
                             const float* __restrict__ node_w1, const float* __restrict__ node_w2,
                             u16* __restrict__ pw) {
  int id = blockIdx.x * 256 + threadIdx.x;
  if (id >= 4 * 6 * 16384 + 512) return;
  if (id >= 4 * 6 * 16384) {
    int id2 = id - 4 * 6 * 16384;
    int l = id2 >> 7, n = id2 & 127;
    pw[id] = f2bf(msg_w1[(l * 257 + 256) * 128 + n]);
    return;
  }
  int l = id / (6 * 16384);
  int rem = id % (6 * 16384);
  int m = rem / 16384;
  int e = rem % 16384;
  int kg = e >> 10;
  int n = (e >> 3) & 127;
  int j = e & 7;
  int k = kg * 8 + j;
  float v = 0.f;
  switch (m) {
    case 0: v = msg_w1[(l * 257 + k) * 128 + n]; break;
    case 1: v = msg_w1[(l * 257 + 128 + k) * 128 + n]; break;
    case 2: v = msg_w2[(l * 128 + k) * 128 + n]; break;
    case 3: v = node_w1[(l * 256 + k) * 128 + n]; break;
    case 4: v = node_w1[(l * 256 + 128 + k) * 128 + n]; break;
    case 5: v = node_w2[(l * 128 + k) * 128 + n]; break;
  }
  pw[id] = f2bf(v);
}

__global__ void embed_kernel(const float* __restrict__ x, const float* __restrict__ emb_w,
                             const float* __restrict__ emb_b, u16* __restrict__ h, int N) {
  int id = blockIdx.x * 256 + threadIdx.x;
  if (id >= N * HN) return;
  int n = id >> 7, c = id & 127;
  h[id] = f2bf(x[n] * emb_w[c] + emb_b[c]);
}

__global__ void dist_kernel(const int* __restrict__ eidx, const float* __restrict__ pos,
                            float* __restrict__ dist, int E) {
  int e = blockIdx.x * 256 + threadIdx.x;
  if (e >= E) return;
  int r = eidx[e], c = eidx[E + e];
  float dx = pos[r * 3 + 0] - pos[c * 3 + 0];
  float dy = pos[r * 3 + 1] - pos[c * 3 + 1];
  float dz = pos[r * 3 + 2] - pos[c * 3 + 2];
  dist[e] = dx * dx + dy * dy + dz * dz;
}

// ---- counting sort of edges by target ----
__global__ void hist_kernel(const int* __restrict__ eidx, int* __restrict__ deg, int E_) {
  int e = blockIdx.x * 256 + threadIdx.x;
  if (e < E_) atomicAdd(&deg[eidx[E_ + e]], 1);
}

__global__ void scan1_kernel(const int* __restrict__ deg, int* __restrict__ off,
                             int* __restrict__ bsum, int n) {
  __shared__ int s[256];
  int t = threadIdx.x;
  int i = blockIdx.x * 256 + t;
  int v = (i < n) ? deg[i] : 0;
  s[t] = v;
  for (int d = 1; d < 256; d <<= 1) {
    __syncthreads();
    int x = (t >= d) ? s[t - d] : 0;
    __syncthreads();
    s[t] += x;
  }
  __syncthreads();
  if (i < n) off[i] = s[t] - v;
  if (t == 255) bsum[blockIdx.x] = s[255];
}

__global__ void scan2_kernel(int* __restrict__ bsum, int nb) {
  __shared__ int s[256];
  int t = threadIdx.x;
  int v = (t < nb) ? bsum[t] : 0;
  s[t] = v;
  for (int d = 1; d < 256; d <<= 1) {
    __syncthreads();
    int x = (t >= d) ? s[t - d] : 0;
    __syncthreads();
    s[t] += x;
  }
  __syncthreads();
  if (t < nb) bsum[t] = s[t] - v;  // exclusive block offsets
}

__global__ void scan3_kernel(int* __restrict__ off, const int* __restrict__ bsum,
                             int* __restrict__ cursor, int n) {
  int i = blockIdx.x * 256 + threadIdx.x;
  if (i < n) {
    int v = off[i] + bsum[blockIdx.x];
    off[i] = v;
    cursor[i] = v;
  }
}

__global__ void scatter_kernel(const int* __restrict__ eidx, const float* __restrict__ ddist,
                               int* __restrict__ cursor, int* __restrict__ es_src,
                               int* __restrict__ es_tgt, float* __restrict__ es_dist, int E_) {
  int e = blockIdx.x * 256 + threadIdx.x;
  if (e >= E_) return;
  int tg = eidx[E_ + e];
  int p = atomicAdd(&cursor[tg], 1);
  es_src[p] = eidx[e];
  es_tgt[p] = tg;
  es_dist[p] = ddist[e];
}

__device__ __forceinline__ void gemm64(const u16* s_A, const u16* s_W,
                                       int w, int quad, int m16, f32x4 acc[8]) {
#pragma unroll
  for (int ks = 0; ks < 4; ks++) {
    bf16x8 a = *(const bf16x8*)&s_A[(w * 16 + m16) * ASTRIDE + ks * 32 + quad * 8];
#pragma unroll
    for (int ct = 0; ct < 8; ct++) {
      bf16x8 b = *(const bf16x8*)&s_W[(ks * 4 + quad) * 1024 + (ct * 16 + m16) * 8];
      acc[ct] = __builtin_amdgcn_mfma_f32_16x16x32_bf16(a, b, acc[ct], 0, 0, 0);
    }
  }
}

// ---- per-node projections: P = h@W1a + b1, Q = h@W1b (both bf16) ----
__global__ __launch_bounds__(256) void proj_kernel(
    const u16* __restrict__ hbf, u16* __restrict__ Pout, u16* __restrict__ Qout,
    const u16* __restrict__ pw, const float* __restrict__ b1, int nnodes) {
  __shared__ __align__(16) u16 s_A[TM * ASTRIDE];
  __shared__ __align__(16) u16 s_W[16384];
  const int t = threadIdx.x;
  const int w = t >> 6, lane = t & 63, quad = lane >> 4, m16 = lane & 15;
  const int tile0 = blockIdx.x * TM;
  {
    int r = t >> 2, qo = (t & 3) * 32;
    int node = tile0 + r;
    if (node >= nnodes) node = nnodes - 1;
    const int4* src = (const int4*)(hbf + node * HN + qo);
    int4* dst = (int4*)(s_A + r * ASTRIDE + qo);
#pragma unroll
    for (int i = 0; i < 4; i++) dst[i] = src[i];
  }
  {
    const int4* src = (const int4*)pw;
    int4* dst = (int4*)s_W;
#pragma unroll
    for (int i = 0; i < 8; i++) dst[t + i * 256] = src[t + i * 256];
  }
  __syncthreads();
  f32x4 acc[8];
#pragma unroll
  for (int ct = 0; ct < 8; ct++) acc[ct] = {0.f, 0.f, 0.f, 0.f};
  gemm64(s_A, s_W, w, quad, m16, acc);
  __syncthreads();
  {
    const int4* src = (const int4*)(pw + 16384);
    int4* dst = (int4*)s_W;
#pragma unroll
    for (int i = 0; i < 8; i++) dst[t + i * 256] = src[t + i * 256];
  }
  float bb[8];
#pragma unroll
  for (int ct = 0; ct < 8; ct++) bb[ct] = b1[ct * 16 + m16];
#pragma unroll
  for (int ct = 0; ct < 8; ct++)
#pragma unroll
    for (int j = 0; j < 4; j++) {
      int n = tile0 + w * 16 + quad * 4 + j;
      if (n < nnodes) Pout[n * HN + ct * 16 + m16] = f2bf(acc[ct][j] + bb[ct]);
    }
  __syncthreads();
#pragma unroll
  for (int ct = 0; ct < 8; ct++) acc[ct] = {0.f, 0.f, 0.f, 0.f};
  gemm64(s_A, s_W, w, quad, m16, acc);
#pragma unroll
  for (int ct = 0; ct < 8; ct++)
#pragma unroll
    for (int j = 0; j < 4; j++) {
      int n = tile0 + w * 16 + quad * 4 + j;
      if (n < nnodes) Qout[n * HN + ct * 16 + m16] = f2bf(acc[ct][j]);
    }
}

// ---- edge kernel v3: persistent, barrier-free loop, wave-local reduce ----
__global__ __launch_bounds__(256, 3) void edge_kernel(
    const u16* __restrict__ P, const u16* __restrict__ Q,
    float* __restrict__ aggr, const u16* __restrict__ pw2,
    const u16* __restrict__ w1db, const float* __restrict__ b2,
    const int* __restrict__ es_src, const int* __restrict__ es_tgt,
    const float* __restrict__ es_dist, int E_) {
  __shared__ __align__(16) u16 s_W[16384];
  __shared__ __align__(16) u16 s_red[4 * 2080];  // per-wave 16 x 130 bf16

  const int t = threadIdx.x;
  const int w = t >> 6, lane = t & 63, quad = lane >> 4, m16 = lane & 15;

  {
    const int4* src = (const int4*)pw2;
    int4* dst = (int4*)s_W;
#pragma unroll
    for (int i = 0; i < 8; i++) dst[t + i * 256] = src[t + i * 256];
  }

  // loop-invariant: w1d (bf16) at my k-cols; b2 at my out-cols
  int4 wreg[4];
#pragma unroll
  for (int ks = 0; ks < 4; ks++)
    wreg[ks] = *(const int4*)(w1db + ks * 32 + quad * 8);
  float b2r[8];
#pragma unroll
  for (int ct = 0; ct < 8; ct++) b2r[ct] = b2[ct * 16 + m16];

  __syncthreads();

  const int ntiles = (E_ + 63) / 64;
  const int per = (ntiles + EGRID - 1) / EGRID;
  const int bidx = blockIdx.x;
  const int bid = (bidx & 7) * ESLOTS + (bidx >> 3);  // XCD-contiguous chunks
  int tile = bid * per;
  int tend = tile + per;
  if (tend > ntiles) tend = ntiles;
  if (tile >= tend) return;

  u16* red = s_red + w * 2080;

  // prologue: indices + gathers for first tile
  int row = tile * 64 + w * 16 + m16;
  bool rv = row < E_;
  int rc = rv ? row : E_ - 1;
  int tgt_raw = es_tgt[rc];
  int src_raw = es_src[rc];
  float dist_c = es_dist[rc];
  int tgt_c = rv ? tgt_raw : -1;
  int4 pv[4], qv[4];
#pragma unroll
  for (int ks = 0; ks < 4; ks++) {
    pv[ks] = *(const int4*)(P + (size_t)tgt_raw * HN + ks * 32 + quad * 8);
    qv[ks] = *(const int4*)(Q + (size_t)src_raw * HN + ks * 32 + quad * 8);
  }

  while (true) {
    // issue next tile's index loads (latency hidden by elementwise below)
    int nxt = tile + 1;
    bool hasn = nxt < tend;
    int rown = nxt * 64 + w * 16 + m16;
    bool rvn = hasn && (rown < E_);
    int rcn = rvn ? rown : rc;
    int tgt_rawn = es_tgt[rcn];
    int src_rawn = es_src[rcn];
    float dist_n = es_dist[rcn];

    // elementwise: hidden = silu(P[tgt] + Q[src] + d*w1d) in A-frag layout
    bf16x8 afr[4];
#pragma unroll
    for (int ks = 0; ks < 4; ks++) {
      const u16* pu = (const u16*)&pv[ks];
      const u16* qu = (const u16*)&qv[ks];
      const u16* wu = (const u16*)&wreg[ks];
      u16 o[8];
#pragma unroll
      for (int j = 0; j < 8; j++) {
        float v = bf2f(pu[j]) + bf2f(qu[j]) + dist_c * bf2f(wu[j]);
        o[j] = f2bf(silu_f(v));
      }
      afr[ks] = *(bf16x8*)o;
    }

    // issue next tile's gathers (latency hidden by GEMM + reduce)
    int4 pvn[4], qvn[4];
#pragma unroll
    for (int ks = 0; ks < 4; ks++) {
      pvn[ks] = *(const int4*)(P + (size_t)tgt_rawn * HN + ks * 32 + quad * 8);
      qvn[ks] = *(const int4*)(Q + (size_t)src_rawn * HN + ks * 32 + quad * 8);
    }

    // GEMM2: hidden @ W2
    f32x4 acc[8];
#pragma unroll
    for (int ct = 0; ct < 8; ct++) acc[ct] = {0.f, 0.f, 0.f, 0.f};
#pragma unroll
    for (int ks = 0; ks < 4; ks++) {
#pragma unroll
      for (int ct = 0; ct < 8; ct++) {
        bf16x8 bfr = *(const bf16x8*)&s_W[(ks * 4 + quad) * 1024 + (ct * 16 + m16) * 8];
        acc[ct] = __builtin_amdgcn_mfma_f32_16x16x32_bf16(afr[ks], bfr, acc[ct], 0, 0, 0);
      }
    }

    // epilogue: +b2 -> bf16 -> wave-local LDS (row = quad*4+j, col = ct*16+m16)
#pragma unroll
    for (int ct = 0; ct < 8; ct++)
#pragma unroll
      for (int j = 0; j < 4; j++)
        red[(quad * 4 + j) * 130 + ct * 16 + m16] = f2bf(acc[ct][j] + b2r[ct]);

    // wave-local segmented reduce over 16 sorted rows (branch is wave-uniform)
    {
      float s0 = 0.f, s1 = 0.f;
      int cur = __shfl(tgt_c, 0);
#pragma unroll
      for (int r = 0; r < 16; r++) {
        int tg = __shfl(tgt_c, r);
        if (tg != cur) {
          if (cur >= 0) {
            atomicAdd(&aggr[(size_t)cur * HN + lane], s0);
            atomicAdd(&aggr[(size_t)cur * HN + 64 + lane], s1);
          }
          cur = tg; s0 = 0.f; s1 = 0.f;
        }
        s0 += bf2f(red[r * 130 + lane]);
        s1 += bf2f(red[r * 130 + 64 + lane]);
      }
      if (cur >= 0) {
        atomicAdd(&aggr[(size_t)cur * HN + lane], s0);
        atomicAdd(&aggr[(size_t)cur * HN + 64 + lane], s1);
      }
    }

    if (!hasn) break;
    tile = nxt;
    rc = rcn;
    tgt_c = rvn ? tgt_rawn : -1;
    dist_c = dist_n;
#pragma unroll
    for (int ks = 0; ks < 4; ks++) { pv[ks] = pvn[ks]; qv[ks] = qvn[ks]; }
  }
}

// ---- node MLP: h' = silu([h|aggr]@W1 + b1)@W2 + b2 ----
__global__ __launch_bounds__(256) void node_kernel(
    const u16* __restrict__ hbf, const float* __restrict__ aggr_in,
    u16* __restrict__ hout, const u16* __restrict__ pw,
    const float* __restrict__ b1, const float* __restrict__ b2, int nnodes) {
  __shared__ __align__(16) u16 s_A[TM * ASTRIDE];
  __shared__ __align__(16) u16 s_W[16384];
  const int t = threadIdx.x;
  const int w = t >> 6, lane = t & 63, quad = lane >> 4, m16 = lane & 15;
  const int tile0 = blockIdx.x * TM;

  {
    const int4* src = (const int4*)pw;
    int4* dst = (int4*)s_W;
#pragma unroll
    for (int i = 0; i < 8; i++) dst[t + i * 256] = src[t + i * 256];
  }
  {
    int r = t >> 2, qo = (t & 3) * 32;
    int node = tile0 + r;
    if (node >= nnodes) node = nnodes - 1;
    const int4* src = (const int4*)(hbf + node * HN + qo);
    int4* dst = (int4*)(s_A + r * ASTRIDE + qo);
#pragma unroll
    for (int i = 0; i < 4; i++) dst[i] = src[i];
  }
  __syncthreads();

  f32x4 acc[8];
#pragma unroll
  for (int ct = 0; ct < 8; ct++) acc[ct] = {0.f, 0.f, 0.f, 0.f};
  gemm64(s_A, s_W, w, quad, m16, acc);
  __syncthreads();

  {
    const int4* src = (const int4*)(pw + 16384);
    int4* dst = (int4*)s_W;
#pragma unroll
    for (int i = 0; i < 8; i++) dst[t + i * 256] = src[t + i * 256];
  }
  {
    int r = t >> 2, qo = (t & 3) * 32;
    int node = tile0 + r;
    if (node >= nnodes) node = nnodes - 1;
    const float4* src = (const float4*)(aggr_in + node * HN + qo);
    u16* dst = s_A + r * ASTRIDE + qo;
#pragma unroll
    for (int i = 0; i < 8; i++) {
      float4 v = src[i];
      ushort4 o;
      o.x = f2bf(v.x); o.y = f2bf(v.y); o.z = f2bf(v.z); o.w = f2bf(v.w);
      *(ushort4*)(dst + i * 4) = o;
    }
  }
  __syncthreads();
  gemm64(s_A, s_W, w, quad, m16, acc);
  __syncthreads();

  {
    const int4* src = (const int4*)(pw + 32768);
    int4* dst = (int4*)s_W;
#pragma unroll
    for (int i = 0; i < 8; i++) dst[t + i * 256] = src[t + i * 256];
  }
  {
    float bb1[8];
#pragma unroll
    for (int ct = 0; ct < 8; ct++) bb1[ct] = b1[ct * 16 + m16];
#pragma unroll
    for (int ct = 0; ct < 8; ct++)
#pragma unroll
      for (int j = 0; j < 4; j++) {
        int row = w * 16 + quad * 4 + j;
        float xv = acc[ct][j] + bb1[ct];
        s_A[row * ASTRIDE + ct * 16 + m16] = f2bf(silu_f(xv));
      }
  }
  __syncthreads();

#pragma unroll
  for (int ct = 0; ct < 8; ct++) acc[ct] = {0.f, 0.f, 0.f, 0.f};
  gemm64(s_A, s_W, w, quad, m16, acc);

  float bb2[8];
#pragma unroll
  for (int ct = 0; ct < 8; ct++) bb2[ct] = b2[ct * 16 + m16];
#pragma unroll
  for (int ct = 0; ct < 8; ct++)
#pragma unroll
    for (int j = 0; j < 4; j++) {
      int row = w * 16 + quad * 4 + j;
      int n = tile0 + row;
      if (n < nnodes) hout[n * HN + ct * 16 + m16] = f2bf(acc[ct][j] + bb2[ct]);
    }
}

// batch sorted -> per-block running sums, atomic only at segment boundaries
__global__ void pool_kernel(const u16* __restrict__ h, const int* __restrict__ batch,
                            float* __restrict__ g, int N) {
  int c = threadIdx.x;  // 128
  int base = blockIdx.x * 256;
  int cur = -1;
  float sum = 0.f;
  for (int i = 0; i < 256; i++) {
    int n = base + i;
    if (n >= N) break;
    int b = batch[n];
    if (b != cur) {
      if (cur >= 0) atomicAdd(&g[cur * HN + c], sum);
      cur = b; sum = 0.f;
    }
    sum += bf2f(h[n * HN + c]);
  }
  if (cur >= 0) atomicAdd(&g[cur * HN + c], sum);
}

__global__ void out_kernel(const float* __restrict__ g, const float* __restrict__ w1,
                           const float* __restrict__ b1, const float* __restrict__ w2,
                           const float* __restrict__ b2, float* __restrict__ out) {
  int gi = threadIdx.x;  // 64
  float s[32];
#pragma unroll
  for (int c = 0; c < 32; c++) s[c] = b1[c];
  for (int k = 0; k < 128; k++) {
    float gv = g[gi * HN + k];
#pragma unroll
    for (int c = 0; c < 32; c++) s[c] += gv * w1[k * 32 + c];
  }
  float acc = b2[0];
#pragma unroll
  for (int c = 0; c < 32; c++) acc += silu_f(s[c]) * w2[c];
  out[gi] = acc;
}

extern "C" void kernel_launch(void* const* d_in, const int* in_sizes, int n_in,
                              void* d_out, int out_size, void* d_ws, size_t ws_size,
                              hipStream_t stream) {
  const float* x = (const float*)d_in[0];
  const float* pos = (const float*)d_in[1];
  const int* eidx = (const int*)d_in[2];
  const int* batch = (const int*)d_in[3];
  const float* emb_w = (const float*)d_in[4];
  const float* emb_b = (const float*)d_in[5];
  const float* msg_w1 = (const float*)d_in[6];
  const float* msg_b1 = (const float*)d_in[7];
  const float* msg_w2 = (const float*)d_in[8];
  const float* msg_b2 = (const float*)d_in[9];
  const float* node_w1 = (const float*)d_in[10];
  const float* node_b1 = (const float*)d_in[11];
  const float* node_w2 = (const float*)d_in[12];
  const float* node_b2 = (const float*)d_in[13];
  const float* out_w1 = (const float*)d_in[14];
  const float* out_b1 = (const float*)d_in[15];
  const float* out_w2 = (const float*)d_in[16];
  const float* out_b2 = (const float*)d_in[17];
  float* outp = (float*)d_out;

  const int N = 30000, E = 600000, G = 64;
  const size_t NH = (size_t)N * HN;

  u16* hA = (u16*)d_ws;                       // N*128 bf16
  u16* hB = hA + NH;                          // N*128 bf16
  u16* Pp = hB + NH;                          // N*128 bf16
  u16* Qp = Pp + NH;                          // N*128 bf16
  float* aggr = (float*)(Qp + NH);            // N*128 f32
  float* ddist = aggr + NH;                   // E f32
  int* es_src = (int*)(ddist + E);            // E
  int* es_tgt = es_src + E;                   // E
  float* es_dist = (float*)(es_tgt + E);      // E
  int* deg = (int*)(es_dist + E);             // N
  int* off = deg + N;                         // N
  int* cursor = off + N;                      // N
  int* bsum = cursor + N;                     // 128
  float* g = (float*)(bsum + 128);            // 64*128 f32
  u16* pw = (u16*)(g + G * HN);               // 4*6*16384 + 512 bf16

  const int NB = (N + 255) / 256;

  pack_weights<<<(4 * 6 * 16384 + 512 + 255) / 256, 256, 0, stream>>>(msg_w1, msg_w2, node_w1, node_w2, pw);
  embed_kernel<<<(N * HN + 255) / 256, 256, 0, stream>>>(x, emb_w, emb_b, hA, N);
  dist_kernel<<<(E + 255) / 256, 256, 0, stream>>>(eidx, pos, ddist, E);

  // counting sort by target
  hipMemsetAsync(deg, 0, N * sizeof(int), stream);
  hist_kernel<<<(E + 255) / 256, 256, 0, stream>>>(eidx, deg, E);
  scan1_kernel<<<NB, 256, 0, stream>>>(deg, off, bsum, N);
  scan2_kernel<<<1, 256, 0, stream>>>(bsum, NB);
  scan3_kernel<<<NB, 256, 0, stream>>>(off, bsum, cursor, N);
  scatter_kernel<<<(E + 255) / 256, 256, 0, stream>>>(eidx, ddist, cursor, es_src, es_tgt, es_dist, E);

  const u16* w1db_base = pw + (size_t)4 * 6 * 16384;

  u16* hcur = hA;
  u16* hnext = hB;
  for (int l = 0; l < 4; l++) {
    const u16* pwl = pw + (size_t)(l * 6) * 16384;
    proj_kernel<<<(N + TM - 1) / TM, 256, 0, stream>>>(
        hcur, Pp, Qp, pwl, msg_b1 + l * 128, N);
    hipMemsetAsync(aggr, 0, NH * sizeof(float), stream);
    edge_kernel<<<EGRID, 256, 0, stream>>>(
        Pp, Qp, aggr, pwl + 2 * 16384,
        w1db_base + l * 128,
        msg_b2 + l * 128, es_src, es_tgt, es_dist, E);
    node_kernel<<<(N + TM - 1) / TM, 256, 0, stream>>>(
        hcur, aggr, hnext, pwl + 3 * 16384,
        node_b1 + l * 128, node_b2 + l * 128, N);
    u16* tmp = hcur; hcur = hnext; hnext = tmp;
  }

  hipMemsetAsync(g, 0, (size_t)G * HN * sizeof(float), stream);
  pool_kernel<<<(N + 255) / 256, 128, 0, stream>>>(hcur, batch, g, N);
  out_kernel<<<1, 64, 0, stream>>>(g, out_w1, out_b1, out_w2, out_b2, outp);
}

// Round 4
// 1063.101 us; speedup vs baseline: 1.0396x; 1.0396x over previous
//
#include <hip/hip_runtime.h>

typedef unsigned short u16;
typedef __bf16 bf16x8 __attribute__((ext_vector_type(8)));
typedef float f32x4 __attribute__((ext_vector_type(4)));

#define HN 128
#define TM 64
#define ASTRIDE 136   // 128 + 8 pad (u16), rows 16B-aligned
#define EGRID 768

__device__ __forceinline__ u16 f2bf(float f) {
  union { float f; unsigned u; } v; v.f = f;
  unsigned r = v.u + 0x7fffu + ((v.u >> 16) & 1u);
  return (u16)(r >> 16);
}
__device__ __forceinline__ float bf2f(u16 v) {
  union { unsigned u; float f; } x; x.u = ((unsigned)v) << 16; return x.f;
}
__device__ __forceinline__ float silu_f(float x) { return x / (1.f + __expf(-x)); }

// ---- pack weights into MFMA B-fragment layout: P[kg][n][8], kg=k/8 ----
// mats per layer: 0=msgW1a 1=msgW1b 2=msgW2 3=nodeW1a 4=nodeW1b 5=nodeW2
// tail region: per-layer w1d (dist column of msg_w1) as bf16 [4][128]
__global__ void pack_weights(const float* __restrict__ msg_w1, const float* __restrict__ msg_w2,
                             const float* __restrict__ node_w1, const float* __restrict__ node_w2,
                             u16* __restrict__ pw) {
  int id = blockIdx.x * 256 + threadIdx.x;
  if (id >= 4 * 6 * 16384 + 512) return;
  if (id >= 4 * 6 * 16384) {
    int id2 = id - 4 * 6 * 16384;
    int l = id2 >> 7, n = id2 & 127;
    pw[id] = f2bf(msg_w1[(l * 257 + 256) * 128 + n]);
    return;
  }
  int l = id / (6 * 16384);
  int rem = id % (6 * 16384);
  int m = rem / 16384;
  int e = rem % 16384;
  int kg = e >> 10;
  int n = (e >> 3) & 127;
  int j = e & 7;
  int k = kg * 8 + j;
  float v = 0.f;
  switch (m) {
    case 0: v = msg_w1[(l * 257 + k) * 128 + n]; break;
    case 1: v = msg_w1[(l * 257 + 128 + k) * 128 + n]; break;
    case 2: v = msg_w2[(l * 128 + k) * 128 + n]; break;
    case 3: v = node_w1[(l * 256 + k) * 128 + n]; break;
    case 4: v = node_w1[(l * 256 + 128 + k) * 128 + n]; break;
    case 5: v = node_w2[(l * 128 + k) * 128 + n]; break;
  }
  pw[id] = f2bf(v);
}

__global__ void embed_kernel(const float* __restrict__ x, const float* __restrict__ emb_w,
                             const float* __restrict__ emb_b, u16* __restrict__ h, int N) {
  int id = blockIdx.x * 256 + threadIdx.x;
  if (id >= N * HN) return;
  int n = id >> 7, c = id & 127;
  h[id] = f2bf(x[n] * emb_w[c] + emb_b[c]);
}

__global__ void dist_kernel(const int* __restrict__ eidx, const float* __restrict__ pos,
                            float* __restrict__ dist, int E) {
  int e = blockIdx.x * 256 + threadIdx.x;
  if (e >= E) return;
  int r = eidx[e], c = eidx[E + e];
  float dx = pos[r * 3 + 0] - pos[c * 3 + 0];
  float dy = pos[r * 3 + 1] - pos[c * 3 + 1];
  float dz = pos[r * 3 + 2] - pos[c * 3 + 2];
  dist[e] = dx * dx + dy * dy + dz * dz;
}

// ---- counting sort of edges by target ----
__global__ void hist_kernel(const int* __restrict__ eidx, int* __restrict__ deg, int E_) {
  int e = blockIdx.x * 256 + threadIdx.x;
  if (e < E_) atomicAdd(&deg[eidx[E_ + e]], 1);
}

__global__ void scan1_kernel(const int* __restrict__ deg, int* __restrict__ off,
                             int* __restrict__ bsum, int n) {
  __shared__ int s[256];
  int t = threadIdx.x;
  int i = blockIdx.x * 256 + t;
  int v = (i < n) ? deg[i] : 0;
  s[t] = v;
  for (int d = 1; d < 256; d <<= 1) {
    __syncthreads();
    int x = (t >= d) ? s[t - d] : 0;
    __syncthreads();
    s[t] += x;
  }
  __syncthreads();
  if (i < n) off[i] = s[t] - v;
  if (t == 255) bsum[blockIdx.x] = s[255];
}

__global__ void scan2_kernel(int* __restrict__ bsum, int nb) {
  __shared__ int s[256];
  int t = threadIdx.x;
  int v = (t < nb) ? bsum[t] : 0;
  s[t] = v;
  for (int d = 1; d < 256; d <<= 1) {
    __syncthreads();
    int x = (t >= d) ? s[t - d] : 0;
    __syncthreads();
    s[t] += x;
  }
  __syncthreads();
  if (t < nb) bsum[t] = s[t] - v;  // exclusive block offsets
}

__global__ void scan3_kernel(int* __restrict__ off, const int* __restrict__ bsum,
                             int* __restrict__ cursor, int n) {
  int i = blockIdx.x * 256 + threadIdx.x;
  if (i < n) {
    int v = off[i] + bsum[blockIdx.x];
    off[i] = v;
    cursor[i] = v;
  }
}

__global__ void scatter_kernel(const int* __restrict__ eidx, const float* __restrict__ ddist,
                               int* __restrict__ cursor, int* __restrict__ es_src,
                               int* __restrict__ es_tgt, float* __restrict__ es_dist, int E_) {
  int e = blockIdx.x * 256 + threadIdx.x;
  if (e >= E_) return;
  int tg = eidx[E_ + e];
  int p = atomicAdd(&cursor[tg], 1);
  es_src[p] = eidx[e];
  es_tgt[p] = tg;
  es_dist[p] = ddist[e];
}

__device__ __forceinline__ void gemm64(const u16* s_A, const u16* s_W,
                                       int w, int quad, int m16, f32x4 acc[8]) {
#pragma unroll
  for (int ks = 0; ks < 4; ks++) {
    bf16x8 a = *(const bf16x8*)&s_A[(w * 16 + m16) * ASTRIDE + ks * 32 + quad * 8];
#pragma unroll
    for (int ct = 0; ct < 8; ct++) {
      bf16x8 b = *(const bf16x8*)&s_W[(ks * 4 + quad) * 1024 + (ct * 16 + m16) * 8];
      acc[ct] = __builtin_amdgcn_mfma_f32_16x16x32_bf16(a, b, acc[ct], 0, 0, 0);
    }
  }
}

// ---- per-node projections (layer 0 only): P = h@W1a + b1, Q = h@W1b ----
__global__ __launch_bounds__(256) void proj_kernel(
    const u16* __restrict__ hbf, u16* __restrict__ Pout, u16* __restrict__ Qout,
    const u16* __restrict__ pw, const float* __restrict__ b1, int nnodes) {
  __shared__ __align__(16) u16 s_A[TM * ASTRIDE];
  __shared__ __align__(16) u16 s_W[16384];
  const int t = threadIdx.x;
  const int w = t >> 6, lane = t & 63, quad = lane >> 4, m16 = lane & 15;
  const int tile0 = blockIdx.x * TM;
  {
    int r = t >> 2, qo = (t & 3) * 32;
    int node = tile0 + r;
    if (node >= nnodes) node = nnodes - 1;
    const int4* src = (const int4*)(hbf + node * HN + qo);
    int4* dst = (int4*)(s_A + r * ASTRIDE + qo);
#pragma unroll
    for (int i = 0; i < 4; i++) dst[i] = src[i];
  }
  {
    const int4* src = (const int4*)pw;
    int4* dst = (int4*)s_W;
#pragma unroll
    for (int i = 0; i < 8; i++) dst[t + i * 256] = src[t + i * 256];
  }
  __syncthreads();
  f32x4 acc[8];
#pragma unroll
  for (int ct = 0; ct < 8; ct++) acc[ct] = {0.f, 0.f, 0.f, 0.f};
  gemm64(s_A, s_W, w, quad, m16, acc);
  __syncthreads();
  {
    const int4* src = (const int4*)(pw + 16384);
    int4* dst = (int4*)s_W;
#pragma unroll
    for (int i = 0; i < 8; i++) dst[t + i * 256] = src[t + i * 256];
  }
  float bb[8];
#pragma unroll
  for (int ct = 0; ct < 8; ct++) bb[ct] = b1[ct * 16 + m16];
#pragma unroll
  for (int ct = 0; ct < 8; ct++)
#pragma unroll
    for (int j = 0; j < 4; j++) {
      int n = tile0 + w * 16 + quad * 4 + j;
      if (n < nnodes) Pout[n * HN + ct * 16 + m16] = f2bf(acc[ct][j] + bb[ct]);
    }
  __syncthreads();
#pragma unroll
  for (int ct = 0; ct < 8; ct++) acc[ct] = {0.f, 0.f, 0.f, 0.f};
  gemm64(s_A, s_W, w, quad, m16, acc);
#pragma unroll
  for (int ct = 0; ct < 8; ct++)
#pragma unroll
    for (int j = 0; j < 4; j++) {
      int n = tile0 + w * 16 + quad * 4 + j;
      if (n < nnodes) Qout[n * HN + ct * 16 + m16] = f2bf(acc[ct][j]);
    }
}

// ---- edge kernel v4: persistent, lockstep-strided tiles (locality window),
// barrier-free inner loop, wave-local segmented reduce ----
__global__ __launch_bounds__(256, 3) void edge_kernel(
    const u16* __restrict__ P, const u16* __restrict__ Q,
    float* __restrict__ aggr, const u16* __restrict__ pw2,
    const u16* __restrict__ w1db, const float* __restrict__ b2,
    const int* __restrict__ es_src, const int* __restrict__ es_tgt,
    const float* __restrict__ es_dist, int E_) {
  __shared__ __align__(16) u16 s_W[16384];
  __shared__ __align__(16) u16 s_red[4 * 2080];  // per-wave 16 x 130 bf16

  const int t = threadIdx.x;
  const int w = t >> 6, lane = t & 63, quad = lane >> 4, m16 = lane & 15;

  {
    const int4* src = (const int4*)pw2;
    int4* dst = (int4*)s_W;
#pragma unroll
    for (int i = 0; i < 8; i++) dst[t + i * 256] = src[t + i * 256];
  }

  // loop-invariant: w1d (bf16) at my k-cols; b2 at my out-cols
  int4 wreg[4];
#pragma unroll
  for (int ks = 0; ks < 4; ks++)
    wreg[ks] = *(const int4*)(w1db + ks * 32 + quad * 8);
  float b2r[8];
#pragma unroll
  for (int ct = 0; ct < 8; ct++) b2r[ct] = b2[ct * 16 + m16];

  __syncthreads();

  const int ntiles = (E_ + 63) / 64;
  int tile = blockIdx.x;
  if (tile >= ntiles) return;

  u16* red = s_red + w * 2080;

  // prologue: indices + gathers for first tile
  int row = tile * 64 + w * 16 + m16;
  bool rv = row < E_;
  int rc = rv ? row : E_ - 1;
  int tgt_raw = es_tgt[rc];
  int src_raw = es_src[rc];
  float dist_c = es_dist[rc];
  int tgt_c = rv ? tgt_raw : -1;
  int4 pv[4], qv[4];
#pragma unroll
  for (int ks = 0; ks < 4; ks++) {
    pv[ks] = *(const int4*)(P + (size_t)tgt_raw * HN + ks * 32 + quad * 8);
    qv[ks] = *(const int4*)(Q + (size_t)src_raw * HN + ks * 32 + quad * 8);
  }

  while (true) {
    // issue next tile's index loads (latency hidden by elementwise below)
    int nxt = tile + EGRID;
    bool hasn = nxt < ntiles;
    int rown = nxt * 64 + w * 16 + m16;
    bool rvn = hasn && (rown < E_);
    int rcn = rvn ? rown : rc;
    int tgt_rawn = es_tgt[rcn];
    int src_rawn = es_src[rcn];
    float dist_n = es_dist[rcn];

    // elementwise: hidden = silu(P[tgt] + Q[src] + d*w1d) in A-frag layout
    bf16x8 afr[4];
#pragma unroll
    for (int ks = 0; ks < 4; ks++) {
      const u16* pu = (const u16*)&pv[ks];
      const u16* qu = (const u16*)&qv[ks];
      const u16* wu = (const u16*)&wreg[ks];
      u16 o[8];
#pragma unroll
      for (int j = 0; j < 8; j++) {
        float v = bf2f(pu[j]) + bf2f(qu[j]) + dist_c * bf2f(wu[j]);
        o[j] = f2bf(silu_f(v));
      }
      afr[ks] = *(bf16x8*)o;
    }

    // issue next tile's gathers (latency hidden by GEMM + reduce)
    int4 pvn[4], qvn[4];
#pragma unroll
    for (int ks = 0; ks < 4; ks++) {
      pvn[ks] = *(const int4*)(P + (size_t)tgt_rawn * HN + ks * 32 + quad * 8);
      qvn[ks] = *(const int4*)(Q + (size_t)src_rawn * HN + ks * 32 + quad * 8);
    }

    // GEMM2: hidden @ W2
    f32x4 acc[8];
#pragma unroll
    for (int ct = 0; ct < 8; ct++) acc[ct] = {0.f, 0.f, 0.f, 0.f};
#pragma unroll
    for (int ks = 0; ks < 4; ks++) {
#pragma unroll
      for (int ct = 0; ct < 8; ct++) {
        bf16x8 bfr = *(const bf16x8*)&s_W[(ks * 4 + quad) * 1024 + (ct * 16 + m16) * 8];
        acc[ct] = __builtin_amdgcn_mfma_f32_16x16x32_bf16(afr[ks], bfr, acc[ct], 0, 0, 0);
      }
    }

    // epilogue: +b2 -> bf16 -> wave-local LDS (row = quad*4+j, col = ct*16+m16)
#pragma unroll
    for (int ct = 0; ct < 8; ct++)
#pragma unroll
      for (int j = 0; j < 4; j++)
        red[(quad * 4 + j) * 130 + ct * 16 + m16] = f2bf(acc[ct][j] + b2r[ct]);

    // wave-local segmented reduce over 16 sorted rows (branch is wave-uniform)
    {
      float s0 = 0.f, s1 = 0.f;
      int cur = __shfl(tgt_c, 0);
#pragma unroll
      for (int r = 0; r < 16; r++) {
        int tg = __shfl(tgt_c, r);
        if (tg != cur) {
          if (cur >= 0) {
            atomicAdd(&aggr[(size_t)cur * HN + lane], s0);
            atomicAdd(&aggr[(size_t)cur * HN + 64 + lane], s1);
          }
          cur = tg; s0 = 0.f; s1 = 0.f;
        }
        s0 += bf2f(red[r * 130 + lane]);
        s1 += bf2f(red[r * 130 + 64 + lane]);
      }
      if (cur >= 0) {
        atomicAdd(&aggr[(size_t)cur * HN + lane], s0);
        atomicAdd(&aggr[(size_t)cur * HN + 64 + lane], s1);
      }
    }

    if (!hasn) break;
    tile = nxt;
    rc = rcn;
    tgt_c = rvn ? tgt_rawn : -1;
    dist_c = dist_n;
#pragma unroll
    for (int ks = 0; ks < 4; ks++) { pv[ks] = pvn[ks]; qv[ks] = qvn[ks]; }
  }
}

// ---- node MLP (+optionally fused next-layer projections) ----
// h' = silu([h|aggr]@W1 + b1)@W2 + b2 ; if FUSE: P = h'@W1a' + b1', Q = h'@W1b'
template <bool FUSE>
__global__ __launch_bounds__(256) void node_kernel(
    const u16* __restrict__ hbf, const float* __restrict__ aggr_in,
    u16* __restrict__ hout, const u16* __restrict__ pw,
    const float* __restrict__ b1, const float* __restrict__ b2,
    const u16* __restrict__ pw_next, const float* __restrict__ b1_next,
    u16* __restrict__ Pout, u16* __restrict__ Qout, int nnodes) {
  __shared__ __align__(16) u16 s_A[TM * ASTRIDE];
  __shared__ __align__(16) u16 s_W[16384];
  const int t = threadIdx.x;
  const int w = t >> 6, lane = t & 63, quad = lane >> 4, m16 = lane & 15;
  const int tile0 = blockIdx.x * TM;

  {
    const int4* src = (const int4*)pw;
    int4* dst = (int4*)s_W;
#pragma unroll
    for (int i = 0; i < 8; i++) dst[t + i * 256] = src[t + i * 256];
  }
  {
    int r = t >> 2, qo = (t & 3) * 32;
    int node = tile0 + r;
    if (node >= nnodes) node = nnodes - 1;
    const int4* src = (const int4*)(hbf + node * HN + qo);
    int4* dst = (int4*)(s_A + r * ASTRIDE + qo);
#pragma unroll
    for (int i = 0; i < 4; i++) dst[i] = src[i];
  }
  __syncthreads();

  f32x4 acc[8];
#pragma unroll
  for (int ct = 0; ct < 8; ct++) acc[ct] = {0.f, 0.f, 0.f, 0.f};
  gemm64(s_A, s_W, w, quad, m16, acc);
  __syncthreads();

  {
    const int4* src = (const int4*)(pw + 16384);
    int4* dst = (int4*)s_W;
#pragma unroll
    for (int i = 0; i < 8; i++) dst[t + i * 256] = src[t + i * 256];
  }
  {
    int r = t >> 2, qo = (t & 3) * 32;
    int node = tile0 + r;
    if (node >= nnodes) node = nnodes - 1;
    const float4* src = (const float4*)(aggr_in + node * HN + qo);
    u16* dst = s_A + r * ASTRIDE + qo;
#pragma unroll
    for (int i = 0; i < 8; i++) {
      float4 v = src[i];
      ushort4 o;
      o.x = f2bf(v.x); o.y = f2bf(v.y); o.z = f2bf(v.z); o.w = f2bf(v.w);
      *(ushort4*)(dst + i * 4) = o;
    }
  }
  __syncthreads();
  gemm64(s_A, s_W, w, quad, m16, acc);
  __syncthreads();

  {
    const int4* src = (const int4*)(pw + 32768);
    int4* dst = (int4*)s_W;
#pragma unroll
    for (int i = 0; i < 8; i++) dst[t + i * 256] = src[t + i * 256];
  }
  {
    float bb1[8];
#pragma unroll
    for (int ct = 0; ct < 8; ct++) bb1[ct] = b1[ct * 16 + m16];
    // s_A rows [w*16, w*16+16) are wave-private: no barrier needed for this write
#pragma unroll
    for (int ct = 0; ct < 8; ct++)
#pragma unroll
      for (int j = 0; j < 4; j++) {
        int row = w * 16 + quad * 4 + j;
        float xv = acc[ct][j] + bb1[ct];
        s_A[row * ASTRIDE + ct * 16 + m16] = f2bf(silu_f(xv));
      }
  }
  __syncthreads();

#pragma unroll
  for (int ct = 0; ct < 8; ct++) acc[ct] = {0.f, 0.f, 0.f, 0.f};
  gemm64(s_A, s_W, w, quad, m16, acc);

  float bb2[8];
#pragma unroll
  for (int ct = 0; ct < 8; ct++) bb2[ct] = b2[ct * 16 + m16];
#pragma unroll
  for (int ct = 0; ct < 8; ct++)
#pragma unroll
    for (int j = 0; j < 4; j++) {
      int row = w * 16 + quad * 4 + j;
      int n = tile0 + row;
      if (n < nnodes) hout[n * HN + ct * 16 + m16] = f2bf(acc[ct][j] + bb2[ct]);
    }

  if (FUSE) {
    // stage h' into s_A (wave-private rows) for the next-layer projections
#pragma unroll
    for (int ct = 0; ct < 8; ct++)
#pragma unroll
      for (int j = 0; j < 4; j++) {
        int row = w * 16 + quad * 4 + j;
        s_A[row * ASTRIDE + ct * 16 + m16] = f2bf(acc[ct][j] + bb2[ct]);
      }
    __syncthreads();  // all gemm s_W reads done before overwrite
    {
      const int4* src = (const int4*)pw_next;
      int4* dst = (int4*)s_W;
#pragma unroll
      for (int i = 0; i < 8; i++) dst[t + i * 256] = src[t + i * 256];
    }
    __syncthreads();
#pragma unroll
    for (int ct = 0; ct < 8; ct++) acc[ct] = {0.f, 0.f, 0.f, 0.f};
    gemm64(s_A, s_W, w, quad, m16, acc);
    {
      float bbn[8];
#pragma unroll
      for (int ct = 0; ct < 8; ct++) bbn[ct] = b1_next[ct * 16 + m16];
#pragma unroll
      for (int ct = 0; ct < 8; ct++)
#pragma unroll
        for (int j = 0; j < 4; j++) {
          int n = tile0 + w * 16 + quad * 4 + j;
          if (n < nnodes) Pout[n * HN + ct * 16 + m16] = f2bf(acc[ct][j] + bbn[ct]);
        }
    }
    __syncthreads();
    {
      const int4* src = (const int4*)(pw_next + 16384);
      int4* dst = (int4*)s_W;
#pragma unroll
      for (int i = 0; i < 8; i++) dst[t + i * 256] = src[t + i * 256];
    }
    __syncthreads();
#pragma unroll
    for (int ct = 0; ct < 8; ct++) acc[ct] = {0.f, 0.f, 0.f, 0.f};
    gemm64(s_A, s_W, w, quad, m16, acc);
#pragma unroll
    for (int ct = 0; ct < 8; ct++)
#pragma unroll
      for (int j = 0; j < 4; j++) {
        int n = tile0 + w * 16 + quad * 4 + j;
        if (n < nnodes) Qout[n * HN + ct * 16 + m16] = f2bf(acc[ct][j]);
      }
  }
}

// batch sorted -> per-block running sums, atomic only at segment boundaries
__global__ void pool_kernel(const u16* __restrict__ h, const int* __restrict__ batch,
                            float* __restrict__ g, int N) {
  int c = threadIdx.x;  // 128
  int base = blockIdx.x * 256;
  int cur = -1;
  float sum = 0.f;
  for (int i = 0; i < 256; i++) {
    int n = base + i;
    if (n >= N) break;
    int b = batch[n];
    if (b != cur) {
      if (cur >= 0) atomicAdd(&g[cur * HN + c], sum);
      cur = b; sum = 0.f;
    }
    sum += bf2f(h[n * HN + c]);
  }
  if (cur >= 0) atomicAdd(&g[cur * HN + c], sum);
}

__global__ void out_kernel(const float* __restrict__ g, const float* __restrict__ w1,
                           const float* __restrict__ b1, const float* __restrict__ w2,
                           const float* __restrict__ b2, float* __restrict__ out) {
  int gi = threadIdx.x;  // 64
  float s[32];
#pragma unroll
  for (int c = 0; c < 32; c++) s[c] = b1[c];
  for (int k = 0; k < 128; k++) {
    float gv = g[gi * HN + k];
#pragma unroll
    for (int c = 0; c < 32; c++) s[c] += gv * w1[k * 32 + c];
  }
  float acc = b2[0];
#pragma unroll
  for (int c = 0; c < 32; c++) acc += silu_f(s[c]) * w2[c];
  out[gi] = acc;
}

extern "C" void kernel_launch(void* const* d_in, const int* in_sizes, int n_in,
                              void* d_out, int out_size, void* d_ws, size_t ws_size,
                              hipStream_t stream) {
  const float* x = (const float*)d_in[0];
  const float* pos = (const float*)d_in[1];
  const int* eidx = (const int*)d_in[2];
  const int* batch = (const int*)d_in[3];
  const float* emb_w = (const float*)d_in[4];
  const float* emb_b = (const float*)d_in[5];
  const float* msg_w1 = (const float*)d_in[6];
  const float* msg_b1 = (const float*)d_in[7];
  const float* msg_w2 = (const float*)d_in[8];
  const float* msg_b2 = (const float*)d_in[9];
  const float* node_w1 = (const float*)d_in[10];
  const float* node_b1 = (const float*)d_in[11];
  const float* node_w2 = (const float*)d_in[12];
  const float* node_b2 = (const float*)d_in[13];
  const float* out_w1 = (const float*)d_in[14];
  const float* out_b1 = (const float*)d_in[15];
  const float* out_w2 = (const float*)d_in[16];
  const float* out_b2 = (const float*)d_in[17];
  float* outp = (float*)d_out;

  const int N = 30000, E = 600000, G = 64;
  const size_t NH = (size_t)N * HN;

  u16* hA = (u16*)d_ws;                       // N*128 bf16
  u16* hB = hA + NH;                          // N*128 bf16
  u16* Pp = hB + NH;                          // N*128 bf16
  u16* Qp = Pp + NH;                          // N*128 bf16
  float* aggr = (float*)(Qp + NH);            // N*128 f32
  float* ddist = aggr + NH;                   // E f32
  int* es_src = (int*)(ddist + E);            // E
  int* es_tgt = es_src + E;                   // E
  float* es_dist = (float*)(es_tgt + E);      // E
  int* deg = (int*)(es_dist + E);             // N
  int* off = deg + N;                         // N
  int* cursor = off + N;                      // N
  int* bsum = cursor + N;                     // 128
  float* g = (float*)(bsum + 128);            // 64*128 f32
  u16* pw = (u16*)(g + G * HN);               // 4*6*16384 + 512 bf16

  const int NB = (N + 255) / 256;

  pack_weights<<<(4 * 6 * 16384 + 512 + 255) / 256, 256, 0, stream>>>(msg_w1, msg_w2, node_w1, node_w2, pw);
  embed_kernel<<<(N * HN + 255) / 256, 256, 0, stream>>>(x, emb_w, emb_b, hA, N);
  dist_kernel<<<(E + 255) / 256, 256, 0, stream>>>(eidx, pos, ddist, E);

  // counting sort by target
  hipMemsetAsync(deg, 0, N * sizeof(int), stream);
  hist_kernel<<<(E + 255) / 256, 256, 0, stream>>>(eidx, deg, E);
  scan1_kernel<<<NB, 256, 0, stream>>>(deg, off, bsum, N);
  scan2_kernel<<<1, 256, 0, stream>>>(bsum, NB);
  scan3_kernel<<<NB, 256, 0, stream>>>(off, bsum, cursor, N);
  scatter_kernel<<<(E + 255) / 256, 256, 0, stream>>>(eidx, ddist, cursor, es_src, es_tgt, es_dist, E);

  const u16* w1db_base = pw + (size_t)4 * 6 * 16384;

  // layer-0 projections from embedded h
  proj_kernel<<<(N + TM - 1) / TM, 256, 0, stream>>>(
      hA, Pp, Qp, pw, msg_b1, N);

  u16* hcur = hA;
  u16* hnext = hB;
  for (int l = 0; l < 4; l++) {
    const u16* pwl = pw + (size_t)(l * 6) * 16384;
    hipMemsetAsync(aggr, 0, NH * sizeof(float), stream);
    edge_kernel<<<EGRID, 256, 0, stream>>>(
        Pp, Qp, aggr, pwl + 2 * 16384,
        w1db_base + l * 128,
        msg_b2 + l * 128, es_src, es_tgt, es_dist, E);
    if (l < 3) {
      const u16* pw_next = pw + (size_t)((l + 1) * 6) * 16384;
      node_kernel<true><<<(N + TM - 1) / TM, 256, 0, stream>>>(
          hcur, aggr, hnext, pwl + 3 * 16384,
          node_b1 + l * 128, node_b2 + l * 128,
          pw_next, msg_b1 + (l + 1) * 128, Pp, Qp, N);
    } else {
      node_kernel<false><<<(N + TM - 1) / TM, 256, 0, stream>>>(
          hcur, aggr, hnext, pwl + 3 * 16384,
          node_b1 + l * 128, node_b2 + l * 128,
          nullptr, nullptr, nullptr, nullptr, N);
    }
    u16* tmp = hcur; hcur = hnext; hnext = tmp;
  }

  hipMemsetAsync(g, 0, (size_t)G * HN * sizeof(float), stream);
  pool_kernel<<<(N + 255) / 256, 128, 0, stream>>>(hcur, batch, g, N);
  out_kernel<<<1, 64, 0, stream>>>(g, out_w1, out_b1, out_w2, out_b2, outp);
}

// Round 5
// 718.198 us; speedup vs baseline: 1.5388x; 1.4802x over previous
//
#include <hip/hip_runtime.h>

typedef unsigned short u16;
typedef __bf16 bf16x8 __attribute__((ext_vector_type(8)));
typedef float f32x4 __attribute__((ext_vector_type(4)));

#define HN 128
#define TM 64
#define ASTRIDE 136   // 128 + 8 pad (u16), rows 16B-aligned
#define ECH 128       // edges per block in edge_kernel

__device__ __forceinline__ u16 f2bf(float f) {
  union { float f; unsigned u; } v; v.f = f;
  unsigned r = v.u + 0x7fffu + ((v.u >> 16) & 1u);
  return (u16)(r >> 16);
}
__device__ __forceinline__ float bf2f(u16 v) {
  union { unsigned u; float f; } x; x.u = ((unsigned)v) << 16; return x.f;
}
__device__ __forceinline__ float silu_f(float x) { return x / (1.f + __expf(-x)); }

// ---- pack weights into MFMA B-fragment layout: P[kg][n][8], kg=k/8 ----
// mats per layer: 0=msgW1a 1=msgW1b 2=msgW2 3=nodeW1a 4=nodeW1b 5=nodeW2
__global__ void pack_weights(const float* __restrict__ msg_w1, const float* __restrict__ msg_w2,
                             const float* __restrict__ node_w1, const float* __restrict__ node_w2,
                             u16* __restrict__ pw) {
  int id = blockIdx.x * 256 + threadIdx.x;
  if (id >= 4 * 6 * 16384) return;
  int l = id / (6 * 16384);
  int rem = id % (6 * 16384);
  int m = rem / 16384;
  int e = rem % 16384;
  int kg = e >> 10;
  int n = (e >> 3) & 127;
  int j = e & 7;
  int k = kg * 8 + j;
  float v = 0.f;
  switch (m) {
    case 0: v = msg_w1[(l * 257 + k) * 128 + n]; break;
    case 1: v = msg_w1[(l * 257 + 128 + k) * 128 + n]; break;
    case 2: v = msg_w2[(l * 128 + k) * 128 + n]; break;
    case 3: v = node_w1[(l * 256 + k) * 128 + n]; break;
    case 4: v = node_w1[(l * 256 + 128 + k) * 128 + n]; break;
    case 5: v = node_w2[(l * 128 + k) * 128 + n]; break;
  }
  pw[id] = f2bf(v);
}

__global__ void embed_kernel(const float* __restrict__ x, const float* __restrict__ emb_w,
                             const float* __restrict__ emb_b, u16* __restrict__ h, int N) {
  int id = blockIdx.x * 256 + threadIdx.x;
  if (id >= N * HN) return;
  int n = id >> 7, c = id & 127;
  h[id] = f2bf(x[n] * emb_w[c] + emb_b[c]);
}

__global__ void dist_kernel(const int* __restrict__ eidx, const float* __restrict__ pos,
                            float* __restrict__ dist, int E) {
  int e = blockIdx.x * 256 + threadIdx.x;
  if (e >= E) return;
  int r = eidx[e], c = eidx[E + e];
  float dx = pos[r * 3 + 0] - pos[c * 3 + 0];
  float dy = pos[r * 3 + 1] - pos[c * 3 + 1];
  float dz = pos[r * 3 + 2] - pos[c * 3 + 2];
  dist[e] = dx * dx + dy * dy + dz * dz;
}

// ---- counting sort of edges by target ----
__global__ void hist_kernel(const int* __restrict__ eidx, int* __restrict__ deg, int E_) {
  int e = blockIdx.x * 256 + threadIdx.x;
  if (e < E_) atomicAdd(&deg[eidx[E_ + e]], 1);
}

__global__ void scan1_kernel(const int* __restrict__ deg, int* __restrict__ off,
                             int* __restrict__ bsum, int n) {
  __shared__ int s[256];
  int t = threadIdx.x;
  int i = blockIdx.x * 256 + t;
  int v = (i < n) ? deg[i] : 0;
  s[t] = v;
  for (int d = 1; d < 256; d <<= 1) {
    __syncthreads();
    int x = (t >= d) ? s[t - d] : 0;
    __syncthreads();
    s[t] += x;
  }
  __syncthreads();
  if (i < n) off[i] = s[t] - v;
  if (t == 255) bsum[blockIdx.x] = s[255];
}

__global__ void scan2_kernel(int* __restrict__ bsum, int nb) {
  __shared__ int s[256];
  int t = threadIdx.x;
  int v = (t < nb) ? bsum[t] : 0;
  s[t] = v;
  for (int d = 1; d < 256; d <<= 1) {
    __syncthreads();
    int x = (t >= d) ? s[t - d] : 0;
    __syncthreads();
    s[t] += x;
  }
  __syncthreads();
  if (t < nb) bsum[t] = s[t] - v;  // exclusive block offsets
}

__global__ void scan3_kernel(int* __restrict__ off, const int* __restrict__ bsum,
                             int* __restrict__ cursor, int n) {
  int i = blockIdx.x * 256 + threadIdx.x;
  if (i < n) {
    int v = off[i] + bsum[blockIdx.x];
    off[i] = v;
    cursor[i] = v;
  }
}

__global__ void scatter_kernel(const int* __restrict__ eidx, const float* __restrict__ ddist,
                               int* __restrict__ cursor, int* __restrict__ es_src,
                               int* __restrict__ es_tgt, float* __restrict__ es_dist, int E_) {
  int e = blockIdx.x * 256 + threadIdx.x;
  if (e >= E_) return;
  int tg = eidx[E_ + e];
  int p = atomicAdd(&cursor[tg], 1);
  es_src[p] = eidx[e];
  es_tgt[p] = tg;
  es_dist[p] = ddist[e];
}

__device__ __forceinline__ void gemm64(const u16* s_A, const u16* s_W,
                                       int w, int quad, int m16, f32x4 acc[8]) {
#pragma unroll
  for (int ks = 0; ks < 4; ks++) {
    bf16x8 a = *(const bf16x8*)&s_A[(w * 16 + m16) * ASTRIDE + ks * 32 + quad * 8];
#pragma unroll
    for (int ct = 0; ct < 8; ct++) {
      bf16x8 b = *(const bf16x8*)&s_W[(ks * 4 + quad) * 1024 + (ct * 16 + m16) * 8];
      acc[ct] = __builtin_amdgcn_mfma_f32_16x16x32_bf16(a, b, acc[ct], 0, 0, 0);
    }
  }
}

// ---- per-node projections (layer 0 only): P = h@W1a + b1, Q = h@W1b ----
__global__ __launch_bounds__(256) void proj_kernel(
    const u16* __restrict__ hbf, u16* __restrict__ Pout, u16* __restrict__ Qout,
    const u16* __restrict__ pw, const float* __restrict__ b1, int nnodes) {
  __shared__ __align__(16) u16 s_A[TM * ASTRIDE];
  __shared__ __align__(16) u16 s_W[16384];
  const int t = threadIdx.x;
  const int w = t >> 6, lane = t & 63, quad = lane >> 4, m16 = lane & 15;
  const int tile0 = blockIdx.x * TM;
  {
    int r = t >> 2, qo = (t & 3) * 32;
    int node = tile0 + r;
    if (node >= nnodes) node = nnodes - 1;
    const int4* src = (const int4*)(hbf + node * HN + qo);
    int4* dst = (int4*)(s_A + r * ASTRIDE + qo);
#pragma unroll
    for (int i = 0; i < 4; i++) dst[i] = src[i];
  }
  {
    const int4* src = (const int4*)pw;
    int4* dst = (int4*)s_W;
#pragma unroll
    for (int i = 0; i < 8; i++) dst[t + i * 256] = src[t + i * 256];
  }
  __syncthreads();
  f32x4 acc[8];
#pragma unroll
  for (int ct = 0; ct < 8; ct++) acc[ct] = {0.f, 0.f, 0.f, 0.f};
  gemm64(s_A, s_W, w, quad, m16, acc);
  __syncthreads();
  {
    const int4* src = (const int4*)(pw + 16384);
    int4* dst = (int4*)s_W;
#pragma unroll
    for (int i = 0; i < 8; i++) dst[t + i * 256] = src[t + i * 256];
  }
  float bb[8];
#pragma unroll
  for (int ct = 0; ct < 8; ct++) bb[ct] = b1[ct * 16 + m16];
#pragma unroll
  for (int ct = 0; ct < 8; ct++)
#pragma unroll
    for (int j = 0; j < 4; j++) {
      int n = tile0 + w * 16 + quad * 4 + j;
      if (n < nnodes) Pout[n * HN + ct * 16 + m16] = f2bf(acc[ct][j] + bb[ct]);
    }
  __syncthreads();
#pragma unroll
  for (int ct = 0; ct < 8; ct++) acc[ct] = {0.f, 0.f, 0.f, 0.f};
  gemm64(s_A, s_W, w, quad, m16, acc);
#pragma unroll
  for (int ct = 0; ct < 8; ct++)
#pragma unroll
    for (int j = 0; j < 4; j++) {
      int n = tile0 + w * 16 + quad * 4 + j;
      if (n < nnodes) Qout[n * HN + ct * 16 + m16] = f2bf(acc[ct][j]);
    }
}

// ---- edge kernel v5: NO GEMM. S[i] = sum_e silu(P[tgt]+Q[src]+d*w1d).
// Sorted edges -> per-(half-block, col) running sum; plain store for interior
// segments, atomicAdd only for segments crossing range boundaries. ----
__global__ __launch_bounds__(256) void edge_kernel(
    const u16* __restrict__ P, const u16* __restrict__ Q,
    float* __restrict__ S, const float* __restrict__ w1d,
    const int* __restrict__ es_src, const int* __restrict__ es_tgt,
    const float* __restrict__ es_dist, int E_) {
  __shared__ int s_src[ECH];
  __shared__ int s_tgt[ECH];
  __shared__ float s_dist[ECH];

  const int t = threadIdx.x;
  const int e0 = blockIdx.x * ECH;
  if (t < ECH) {
    int e = e0 + t;
    bool v = e < E_;
    s_src[t] = v ? es_src[e] : 0;
    s_tgt[t] = v ? es_tgt[e] : -1;
    s_dist[t] = v ? es_dist[e] : 0.f;
  }
  __syncthreads();

  int cnt = E_ - e0;
  if (cnt > ECH) cnt = ECH;
  const int c = t & 127;
  const int half = t >> 7;
  const int a = half * (ECH / 2);
  int bnd = a + ECH / 2;
  if (bnd > cnt) bnd = cnt;
  if (a >= bnd) return;

  const float wd = w1d[c];
  // targets adjacent to my range (for boundary-atomic decision)
  const int tprev = (e0 + a > 0) ? es_tgt[e0 + a - 1] : -2;
  const int tnext = (e0 + bnd < E_) ? es_tgt[e0 + bnd] : -2;

  int cur = s_tgt[a];
  float sum = 0.f;
  float pv = bf2f(P[(size_t)cur * HN + c]);
  int srcn = s_src[a];

  for (int i = a; i < bnd; i++) {
    float q = bf2f(Q[(size_t)srcn * HN + c]);  // load for edge i (prefetched idx)
    if (i + 1 < bnd) srcn = s_src[i + 1];
    int tg = s_tgt[i];
    if (tg != cur) {
      float* dst = &S[(size_t)cur * HN + c];
      if (cur == tprev || cur == tnext) atomicAdd(dst, sum);
      else *dst = sum;
      cur = tg;
      sum = 0.f;
      pv = bf2f(P[(size_t)cur * HN + c]);
    }
    sum += silu_f(pv + q + s_dist[i] * wd);
  }
  {
    float* dst = &S[(size_t)cur * HN + c];
    if (cur == tprev || cur == tnext) atomicAdd(dst, sum);
    else *dst = sum;
  }
}

// ---- aggr kernel: aggr_bf16 = S @ msgW2 + deg * b2 ----
__global__ __launch_bounds__(256) void aggr_kernel(
    const float* __restrict__ S, const int* __restrict__ deg,
    const u16* __restrict__ pw2, const float* __restrict__ b2,
    u16* __restrict__ aggr_out, int nnodes) {
  __shared__ __align__(16) u16 s_A[TM * ASTRIDE];
  __shared__ __align__(16) u16 s_W[16384];
  const int t = threadIdx.x;
  const int w = t >> 6, lane = t & 63, quad = lane >> 4, m16 = lane & 15;
  const int tile0 = blockIdx.x * TM;

  {
    const int4* src = (const int4*)pw2;
    int4* dst = (int4*)s_W;
#pragma unroll
    for (int i = 0; i < 8; i++) dst[t + i * 256] = src[t + i * 256];
  }
  {
    int r = t >> 2, qo = (t & 3) * 32;
    int node = tile0 + r;
    if (node >= nnodes) node = nnodes - 1;
    const float4* src = (const float4*)(S + (size_t)node * HN + qo);
    u16* dst = s_A + r * ASTRIDE + qo;
#pragma unroll
    for (int i = 0; i < 8; i++) {
      float4 v = src[i];
      ushort4 o;
      o.x = f2bf(v.x); o.y = f2bf(v.y); o.z = f2bf(v.z); o.w = f2bf(v.w);
      *(ushort4*)(dst + i * 4) = o;
    }
  }
  __syncthreads();

  f32x4 acc[8];
#pragma unroll
  for (int ct = 0; ct < 8; ct++) acc[ct] = {0.f, 0.f, 0.f, 0.f};
  gemm64(s_A, s_W, w, quad, m16, acc);

  float degv[4];
#pragma unroll
  for (int j = 0; j < 4; j++) {
    int n = tile0 + w * 16 + quad * 4 + j;
    degv[j] = (n < nnodes) ? (float)deg[n] : 0.f;
  }
  float b2r[8];
#pragma unroll
  for (int ct = 0; ct < 8; ct++) b2r[ct] = b2[ct * 16 + m16];
#pragma unroll
  for (int ct = 0; ct < 8; ct++)
#pragma unroll
    for (int j = 0; j < 4; j++) {
      int n = tile0 + w * 16 + quad * 4 + j;
      if (n < nnodes)
        aggr_out[(size_t)n * HN + ct * 16 + m16] = f2bf(acc[ct][j] + degv[j] * b2r[ct]);
    }
}

// ---- node MLP (+optionally fused next-layer projections) ----
// h' = silu([h|aggr]@W1 + b1)@W2 + b2 ; if FUSE: P = h'@W1a' + b1', Q = h'@W1b'
template <bool FUSE>
__global__ __launch_bounds__(256) void node_kernel(
    const u16* __restrict__ hbf, const u16* __restrict__ aggr_in,
    u16* __restrict__ hout, const u16* __restrict__ pw,
    const float* __restrict__ b1, const float* __restrict__ b2,
    const u16* __restrict__ pw_next, const float* __restrict__ b1_next,
    u16* __restrict__ Pout, u16* __restrict__ Qout, int nnodes) {
  __shared__ __align__(16) u16 s_A[TM * ASTRIDE];
  __shared__ __align__(16) u16 s_W[16384];
  const int t = threadIdx.x;
  const int w = t >> 6, lane = t & 63, quad = lane >> 4, m16 = lane & 15;
  const int tile0 = blockIdx.x * TM;

  {
    const int4* src = (const int4*)pw;
    int4* dst = (int4*)s_W;
#pragma unroll
    for (int i = 0; i < 8; i++) dst[t + i * 256] = src[t + i * 256];
  }
  {
    int r = t >> 2, qo = (t & 3) * 32;
    int node = tile0 + r;
    if (node >= nnodes) node = nnodes - 1;
    const int4* src = (const int4*)(hbf + node * HN + qo);
    int4* dst = (int4*)(s_A + r * ASTRIDE + qo);
#pragma unroll
    for (int i = 0; i < 4; i++) dst[i] = src[i];
  }
  __syncthreads();

  f32x4 acc[8];
#pragma unroll
  for (int ct = 0; ct < 8; ct++) acc[ct] = {0.f, 0.f, 0.f, 0.f};
  gemm64(s_A, s_W, w, quad, m16, acc);
  __syncthreads();

  {
    const int4* src = (const int4*)(pw + 16384);
    int4* dst = (int4*)s_W;
#pragma unroll
    for (int i = 0; i < 8; i++) dst[t + i * 256] = src[t + i * 256];
  }
  {
    int r = t >> 2, qo = (t & 3) * 32;
    int node = tile0 + r;
    if (node >= nnodes) node = nnodes - 1;
    const int4* src = (const int4*)(aggr_in + (size_t)node * HN + qo);
    int4* dst = (int4*)(s_A + r * ASTRIDE + qo);
#pragma unroll
    for (int i = 0; i < 4; i++) dst[i] = src[i];
  }
  __syncthreads();
  gemm64(s_A, s_W, w, quad, m16, acc);
  __syncthreads();

  {
    const int4* src = (const int4*)(pw + 32768);
    int4* dst = (int4*)s_W;
#pragma unroll
    for (int i = 0; i < 8; i++) dst[t + i * 256] = src[t + i * 256];
  }
  {
    float bb1[8];
#pragma unroll
    for (int ct = 0; ct < 8; ct++) bb1[ct] = b1[ct * 16 + m16];
    // s_A rows [w*16, w*16+16) are wave-private: no barrier needed for this write
#pragma unroll
    for (int ct = 0; ct < 8; ct++)
#pragma unroll
      for (int j = 0; j < 4; j++) {
        int row = w * 16 + quad * 4 + j;
        float xv = acc[ct][j] + bb1[ct];
        s_A[row * ASTRIDE + ct * 16 + m16] = f2bf(silu_f(xv));
      }
  }
  __syncthreads();

#pragma unroll
  for (int ct = 0; ct < 8; ct++) acc[ct] = {0.f, 0.f, 0.f, 0.f};
  gemm64(s_A, s_W, w, quad, m16, acc);

  float bb2[8];
#pragma unroll
  for (int ct = 0; ct < 8; ct++) bb2[ct] = b2[ct * 16 + m16];
#pragma unroll
  for (int ct = 0; ct < 8; ct++)
#pragma unroll
    for (int j = 0; j < 4; j++) {
      int row = w * 16 + quad * 4 + j;
      int n = tile0 + row;
      if (n < nnodes) hout[n * HN + ct * 16 + m16] = f2bf(acc[ct][j] + bb2[ct]);
    }

  if (FUSE) {
    // stage h' into s_A (wave-private rows) for the next-layer projections
#pragma unroll
    for (int ct = 0; ct < 8; ct++)
#pragma unroll
      for (int j = 0; j < 4; j++) {
        int row = w * 16 + quad * 4 + j;
        s_A[row * ASTRIDE + ct * 16 + m16] = f2bf(acc[ct][j] + bb2[ct]);
      }
    __syncthreads();  // all gemm s_W reads done before overwrite
    {
      const int4* src = (const int4*)pw_next;
      int4* dst = (int4*)s_W;
#pragma unroll
      for (int i = 0; i < 8; i++) dst[t + i * 256] = src[t + i * 256];
    }
    __syncthreads();
#pragma unroll
    for (int ct = 0; ct < 8; ct++) acc[ct] = {0.f, 0.f, 0.f, 0.f};
    gemm64(s_A, s_W, w, quad, m16, acc);
    {
      float bbn[8];
#pragma unroll
      for (int ct = 0; ct < 8; ct++) bbn[ct] = b1_next[ct * 16 + m16];
#pragma unroll
      for (int ct = 0; ct < 8; ct++)
#pragma unroll
        for (int j = 0; j < 4; j++) {
          int n = tile0 + w * 16 + quad * 4 + j;
          if (n < nnodes) Pout[n * HN + ct * 16 + m16] = f2bf(acc[ct][j] + bbn[ct]);
        }
    }
    __syncthreads();
    {
      const int4* src = (const int4*)(pw_next + 16384);
      int4* dst = (int4*)s_W;
#pragma unroll
      for (int i = 0; i < 8; i++) dst[t + i * 256] = src[t + i * 256];
    }
    __syncthreads();
#pragma unroll
    for (int ct = 0; ct < 8; ct++) acc[ct] = {0.f, 0.f, 0.f, 0.f};
    gemm64(s_A, s_W, w, quad, m16, acc);
#pragma unroll
    for (int ct = 0; ct < 8; ct++)
#pragma unroll
      for (int j = 0; j < 4; j++) {
        int n = tile0 + w * 16 + quad * 4 + j;
        if (n < nnodes) Qout[n * HN + ct * 16 + m16] = f2bf(acc[ct][j]);
      }
  }
}

// batch sorted -> per-block running sums, atomic only at segment boundaries
__global__ void pool_kernel(const u16* __restrict__ h, const int* __restrict__ batch,
                            float* __restrict__ g, int N) {
  int c = threadIdx.x;  // 128
  int base = blockIdx.x * 256;
  int cur = -1;
  float sum = 0.f;
  for (int i = 0; i < 256; i++) {
    int n = base + i;
    if (n >= N) break;
    int b = batch[n];
    if (b != cur) {
      if (cur >= 0) atomicAdd(&g[cur * HN + c], sum);
      cur = b; sum = 0.f;
    }
    sum += bf2f(h[n * HN + c]);
  }
  if (cur >= 0) atomicAdd(&g[cur * HN + c], sum);
}

__global__ void out_kernel(const float* __restrict__ g, const float* __restrict__ w1,
                           const float* __restrict__ b1, const float* __restrict__ w2,
                           const float* __restrict__ b2, float* __restrict__ out) {
  int gi = threadIdx.x;  // 64
  float s[32];
#pragma unroll
  for (int c = 0; c < 32; c++) s[c] = b1[c];
  for (int k = 0; k < 128; k++) {
    float gv = g[gi * HN + k];
#pragma unroll
    for (int c = 0; c < 32; c++) s[c] += gv * w1[k * 32 + c];
  }
  float acc = b2[0];
#pragma unroll
  for (int c = 0; c < 32; c++) acc += silu_f(s[c]) * w2[c];
  out[gi] = acc;
}

extern "C" void kernel_launch(void* const* d_in, const int* in_sizes, int n_in,
                              void* d_out, int out_size, void* d_ws, size_t ws_size,
                              hipStream_t stream) {
  const float* x = (const float*)d_in[0];
  const float* pos = (const float*)d_in[1];
  const int* eidx = (const int*)d_in[2];
  const int* batch = (const int*)d_in[3];
  const float* emb_w = (const float*)d_in[4];
  const float* emb_b = (const float*)d_in[5];
  const float* msg_w1 = (const float*)d_in[6];
  const float* msg_b1 = (const float*)d_in[7];
  const float* msg_w2 = (const float*)d_in[8];
  const float* msg_b2 = (const float*)d_in[9];
  const float* node_w1 = (const float*)d_in[10];
  const float* node_b1 = (const float*)d_in[11];
  const float* node_w2 = (const float*)d_in[12];
  const float* node_b2 = (const float*)d_in[13];
  const float* out_w1 = (const float*)d_in[14];
  const float* out_b1 = (const float*)d_in[15];
  const float* out_w2 = (const float*)d_in[16];
  const float* out_b2 = (const float*)d_in[17];
  float* outp = (float*)d_out;

  const int N = 30000, E = 600000, G = 64;
  const size_t NH = (size_t)N * HN;

  u16* hA = (u16*)d_ws;                       // N*128 bf16
  u16* hB = hA + NH;                          // N*128 bf16
  u16* Pp = hB + NH;                          // N*128 bf16
  u16* Qp = Pp + NH;                          // N*128 bf16
  u16* aggrbf = Qp + NH;                      // N*128 bf16
  float* S = (float*)(aggrbf + NH);           // N*128 f32
  float* ddist = S + NH;                      // E f32
  int* es_src = (int*)(ddist + E);            // E
  int* es_tgt = es_src + E;                   // E
  float* es_dist = (float*)(es_tgt + E);      // E
  int* deg = (int*)(es_dist + E);             // N
  int* off = deg + N;                         // N
  int* cursor = off + N;                      // N
  int* bsum = cursor + N;                     // 128
  float* g = (float*)(bsum + 128);            // 64*128 f32
  u16* pw = (u16*)(g + G * HN);               // 4*6*16384 bf16

  const int NB = (N + 255) / 256;

  pack_weights<<<(4 * 6 * 16384 + 255) / 256, 256, 0, stream>>>(msg_w1, msg_w2, node_w1, node_w2, pw);
  embed_kernel<<<(N * HN + 255) / 256, 256, 0, stream>>>(x, emb_w, emb_b, hA, N);
  dist_kernel<<<(E + 255) / 256, 256, 0, stream>>>(eidx, pos, ddist, E);

  // counting sort by target
  hipMemsetAsync(deg, 0, N * sizeof(int), stream);
  hist_kernel<<<(E + 255) / 256, 256, 0, stream>>>(eidx, deg, E);
  scan1_kernel<<<NB, 256, 0, stream>>>(deg, off, bsum, N);
  scan2_kernel<<<1, 256, 0, stream>>>(bsum, NB);
  scan3_kernel<<<NB, 256, 0, stream>>>(off, bsum, cursor, N);
  scatter_kernel<<<(E + 255) / 256, 256, 0, stream>>>(eidx, ddist, cursor, es_src, es_tgt, es_dist, E);

  // layer-0 projections from embedded h
  proj_kernel<<<(N + TM - 1) / TM, 256, 0, stream>>>(hA, Pp, Qp, pw, msg_b1, N);

  u16* hcur = hA;
  u16* hnext = hB;
  for (int l = 0; l < 4; l++) {
    const u16* pwl = pw + (size_t)(l * 6) * 16384;
    hipMemsetAsync(S, 0, NH * sizeof(float), stream);
    edge_kernel<<<(E + ECH - 1) / ECH, 256, 0, stream>>>(
        Pp, Qp, S,
        msg_w1 + (size_t)(l * 257 + 256) * 128,  // w1d row (fp32)
        es_src, es_tgt, es_dist, E);
    aggr_kernel<<<(N + TM - 1) / TM, 256, 0, stream>>>(
        S, deg, pwl + 2 * 16384, msg_b2 + l * 128, aggrbf, N);
    if (l < 3) {
      const u16* pw_next = pw + (size_t)((l + 1) * 6) * 16384;
      node_kernel<true><<<(N + TM - 1) / TM, 256, 0, stream>>>(
          hcur, aggrbf, hnext, pwl + 3 * 16384,
          node_b1 + l * 128, node_b2 + l * 128,
          pw_next, msg_b1 + (l + 1) * 128, Pp, Qp, N);
    } else {
      node_kernel<false><<<(N + TM - 1) / TM, 256, 0, stream>>>(
          hcur, aggrbf, hnext, pwl + 3 * 16384,
          node_b1 + l * 128, node_b2 + l * 128,
          nullptr, nullptr, nullptr, nullptr, N);
    }
    u16* tmp = hcur; hcur = hnext; hnext = tmp;
  }

  hipMemsetAsync(g, 0, (size_t)G * HN * sizeof(float), stream);
  pool_kernel<<<(N + 255) / 256, 128, 0, stream>>>(hcur, batch, g, N);
  out_kernel<<<1, 64, 0, stream>>>(g, out_w1, out_b1, out_w2, out_b2, outp);
}

// Round 6
// 592.966 us; speedup vs baseline: 1.8638x; 1.2112x over previous
//
#include <hip/hip_runtime.h>

typedef unsigned short u16;
typedef __bf16 bf16x8 __attribute__((ext_vector_type(8)));
typedef float f32x4 __attribute__((ext_vector_type(4)));

#define HN 128
#define TM 64
#define ASTRIDE 136   // 128 + 8 pad (u16), rows 16B-aligned
#define ECH 128       // edges per block in edge_kernel

__device__ __forceinline__ u16 f2bf(float f) {
  union { float f; unsigned u; } v; v.f = f;
  unsigned r = v.u + 0x7fffu + ((v.u >> 16) & 1u);
  return (u16)(r >> 16);
}
__device__ __forceinline__ float bf2f(u16 v) {
  union { unsigned u; float f; } x; x.u = ((unsigned)v) << 16; return x.f;
}
__device__ __forceinline__ float silu_f(float x) { return x / (1.f + __expf(-x)); }

// ---- pack weights into MFMA B-fragment layout: P[kg][n][8], kg=k/8 ----
// mats per layer: 0=msgW1a 1=msgW1b 2=msgW2 3=nodeW1a 4=nodeW1b 5=nodeW2
__global__ void pack_weights(const float* __restrict__ msg_w1, const float* __restrict__ msg_w2,
                             const float* __restrict__ node_w1, const float* __restrict__ node_w2,
                             u16* __restrict__ pw) {
  int id = blockIdx.x * 256 + threadIdx.x;
  if (id >= 4 * 6 * 16384) return;
  int l = id / (6 * 16384);
  int rem = id % (6 * 16384);
  int m = rem / 16384;
  int e = rem % 16384;
  int kg = e >> 10;
  int n = (e >> 3) & 127;
  int j = e & 7;
  int k = kg * 8 + j;
  float v = 0.f;
  switch (m) {
    case 0: v = msg_w1[(l * 257 + k) * 128 + n]; break;
    case 1: v = msg_w1[(l * 257 + 128 + k) * 128 + n]; break;
    case 2: v = msg_w2[(l * 128 + k) * 128 + n]; break;
    case 3: v = node_w1[(l * 256 + k) * 128 + n]; break;
    case 4: v = node_w1[(l * 256 + 128 + k) * 128 + n]; break;
    case 5: v = node_w2[(l * 128 + k) * 128 + n]; break;
  }
  pw[id] = f2bf(v);
}

// ---- counting sort of edges by target ----
__global__ void hist_kernel(const int* __restrict__ eidx, int* __restrict__ deg, int E_) {
  int e = blockIdx.x * 256 + threadIdx.x;
  if (e < E_) atomicAdd(&deg[eidx[E_ + e]], 1);
}

__global__ void scan1_kernel(const int* __restrict__ deg, int* __restrict__ off,
                             int* __restrict__ bsum, int n) {
  __shared__ int s[256];
  int t = threadIdx.x;
  int i = blockIdx.x * 256 + t;
  int v = (i < n) ? deg[i] : 0;
  s[t] = v;
  for (int d = 1; d < 256; d <<= 1) {
    __syncthreads();
    int x = (t >= d) ? s[t - d] : 0;
    __syncthreads();
    s[t] += x;
  }
  __syncthreads();
  if (i < n) off[i] = s[t] - v;
  if (t == 255) bsum[blockIdx.x] = s[255];
}

__global__ void scan2_kernel(int* __restrict__ bsum, int nb) {
  __shared__ int s[256];
  int t = threadIdx.x;
  int v = (t < nb) ? bsum[t] : 0;
  s[t] = v;
  for (int d = 1; d < 256; d <<= 1) {
    __syncthreads();
    int x = (t >= d) ? s[t - d] : 0;
    __syncthreads();
    s[t] += x;
  }
  __syncthreads();
  if (t < nb) bsum[t] = s[t] - v;  // exclusive block offsets
}

__global__ void scan3_kernel(int* __restrict__ off, const int* __restrict__ bsum,
                             int* __restrict__ cursor, int n) {
  int i = blockIdx.x * 256 + threadIdx.x;
  if (i < n) {
    int v = off[i] + bsum[blockIdx.x];
    off[i] = v;
    cursor[i] = v;
  }
}

// scatter edges into target-sorted order; dist computed inline (fused dist_kernel)
__global__ void scatter_kernel(const int* __restrict__ eidx, const float* __restrict__ pos,
                               int* __restrict__ cursor, int* __restrict__ es, int E_) {
  int e = blockIdx.x * 256 + threadIdx.x;
  if (e >= E_) return;
  int sr = eidx[e], tg = eidx[E_ + e];
  float dx = pos[sr * 3 + 0] - pos[tg * 3 + 0];
  float dy = pos[sr * 3 + 1] - pos[tg * 3 + 1];
  float dz = pos[sr * 3 + 2] - pos[tg * 3 + 2];
  float d = dx * dx + dy * dy + dz * dz;
  int p = atomicAdd(&cursor[tg], 1);
  es[3 * p + 0] = sr;
  es[3 * p + 1] = tg;
  ((float*)es)[3 * p + 2] = d;
}

__device__ __forceinline__ void gemm64(const u16* s_A, const u16* s_W,
                                       int w, int quad, int m16, f32x4 acc[8]) {
#pragma unroll
  for (int ks = 0; ks < 4; ks++) {
    bf16x8 a = *(const bf16x8*)&s_A[(w * 16 + m16) * ASTRIDE + ks * 32 + quad * 8];
#pragma unroll
    for (int ct = 0; ct < 8; ct++) {
      bf16x8 b = *(const bf16x8*)&s_W[(ks * 4 + quad) * 1024 + (ct * 16 + m16) * 8];
      acc[ct] = __builtin_amdgcn_mfma_f32_16x16x32_bf16(a, b, acc[ct], 0, 0, 0);
    }
  }
}

// ---- proj (layer 0, embed fused): h = x*emb_w+emb_b; P = h@W1a + b1, Q = h@W1b ----
__global__ __launch_bounds__(256) void proj_kernel(
    const float* __restrict__ x, const float* __restrict__ emb_w,
    const float* __restrict__ emb_b, u16* __restrict__ hbf,
    u16* __restrict__ Pout, u16* __restrict__ Qout,
    const u16* __restrict__ pw, const float* __restrict__ b1, int nnodes) {
  __shared__ __align__(16) u16 s_A[TM * ASTRIDE];
  __shared__ __align__(16) u16 s_W[16384];
  const int t = threadIdx.x;
  const int w = t >> 6, lane = t & 63, quad = lane >> 4, m16 = lane & 15;
  const int tile0 = blockIdx.x * TM;
  {
    int r = t >> 2, qo = (t & 3) * 32;
    int node = tile0 + r;
    if (node >= nnodes) node = nnodes - 1;
    float xv = x[node];
    u16 hv[32];
#pragma unroll
    for (int i = 0; i < 32; i++) hv[i] = f2bf(xv * emb_w[qo + i] + emb_b[qo + i]);
    u16* dst = s_A + r * ASTRIDE + qo;
#pragma unroll
    for (int i = 0; i < 4; i++) *(int4*)(dst + i * 8) = *(int4*)(hv + i * 8);
    u16* gd = hbf + (size_t)node * HN + qo;
#pragma unroll
    for (int i = 0; i < 4; i++) *(int4*)(gd + i * 8) = *(int4*)(hv + i * 8);
  }
  {
    const int4* src = (const int4*)pw;
    int4* dst = (int4*)s_W;
#pragma unroll
    for (int i = 0; i < 8; i++) dst[t + i * 256] = src[t + i * 256];
  }
  __syncthreads();
  f32x4 acc[8];
#pragma unroll
  for (int ct = 0; ct < 8; ct++) acc[ct] = {0.f, 0.f, 0.f, 0.f};
  gemm64(s_A, s_W, w, quad, m16, acc);
  __syncthreads();
  {
    const int4* src = (const int4*)(pw + 16384);
    int4* dst = (int4*)s_W;
#pragma unroll
    for (int i = 0; i < 8; i++) dst[t + i * 256] = src[t + i * 256];
  }
  float bb[8];
#pragma unroll
  for (int ct = 0; ct < 8; ct++) bb[ct] = b1[ct * 16 + m16];
#pragma unroll
  for (int ct = 0; ct < 8; ct++)
#pragma unroll
    for (int j = 0; j < 4; j++) {
      int n = tile0 + w * 16 + quad * 4 + j;
      if (n < nnodes) Pout[n * HN + ct * 16 + m16] = f2bf(acc[ct][j] + bb[ct]);
    }
  __syncthreads();
#pragma unroll
  for (int ct = 0; ct < 8; ct++) acc[ct] = {0.f, 0.f, 0.f, 0.f};
  gemm64(s_A, s_W, w, quad, m16, acc);
#pragma unroll
  for (int ct = 0; ct < 8; ct++)
#pragma unroll
    for (int j = 0; j < 4; j++) {
      int n = tile0 + w * 16 + quad * 4 + j;
      if (n < nnodes) Qout[n * HN + ct * 16 + m16] = f2bf(acc[ct][j]);
    }
}

// ---- edge kernel: S[i] = sum_e silu(P[tgt]+Q[src]+d*w1d). Sorted edges ->
// running sums; plain store for interior segments, atomicAdd at boundaries. ----
__global__ __launch_bounds__(256) void edge_kernel(
    const u16* __restrict__ P, const u16* __restrict__ Q,
    float* __restrict__ S, const float* __restrict__ w1d,
    const int* __restrict__ es, int E_) {
  __shared__ int s_src[ECH];
  __shared__ int s_tgt[ECH];
  __shared__ float s_dist[ECH];

  const int t = threadIdx.x;
  const int e0 = blockIdx.x * ECH;
  if (t < ECH) {
    int e = e0 + t;
    if (e < E_) {
      s_src[t] = es[3 * e + 0];
      s_tgt[t] = es[3 * e + 1];
      s_dist[t] = ((const float*)es)[3 * e + 2];
    } else {
      s_src[t] = 0; s_tgt[t] = -1; s_dist[t] = 0.f;
    }
  }
  __syncthreads();

  int cnt = E_ - e0;
  if (cnt > ECH) cnt = ECH;
  const int c = t & 127;
  const int half = t >> 7;
  const int a = half * (ECH / 2);
  int bnd = a + ECH / 2;
  if (bnd > cnt) bnd = cnt;
  if (a >= bnd) return;

  const float wd = w1d[c];
  const int tprev = (e0 + a > 0) ? es[3 * (e0 + a - 1) + 1] : -2;
  const int tnext = (e0 + bnd < E_) ? es[3 * (e0 + bnd) + 1] : -2;

  int cur = s_tgt[a];
  float sum = 0.f;
  float pv = bf2f(P[(size_t)cur * HN + c]);
  int srcn = s_src[a];

  for (int i = a; i < bnd; i++) {
    float q = bf2f(Q[(size_t)srcn * HN + c]);
    if (i + 1 < bnd) srcn = s_src[i + 1];
    int tg = s_tgt[i];
    if (tg != cur) {
      float* dst = &S[(size_t)cur * HN + c];
      if (cur == tprev || cur == tnext) atomicAdd(dst, sum);
      else *dst = sum;
      cur = tg;
      sum = 0.f;
      pv = bf2f(P[(size_t)cur * HN + c]);
    }
    sum += silu_f(pv + q + s_dist[i] * wd);
  }
  {
    float* dst = &S[(size_t)cur * HN + c];
    if (cur == tprev || cur == tnext) atomicAdd(dst, sum);
    else *dst = sum;
  }
}

// ---- node MLP, aggr fused: aggr = S@msgW2 + deg*b2m (re-zeros S);
// h' = silu([h|aggr]@nodeW1 + b1)@nodeW2 + b2; FUSE: next-layer P/Q ----
template <bool FUSE>
__global__ __launch_bounds__(256) void node_kernel(
    const u16* __restrict__ hbf, float* __restrict__ S, const int* __restrict__ deg,
    u16* __restrict__ hout, const u16* __restrict__ pw2m, const float* __restrict__ b2m,
    const u16* __restrict__ pwn, const float* __restrict__ b1, const float* __restrict__ b2,
    const u16* __restrict__ pw_next, const float* __restrict__ b1_next,
    u16* __restrict__ Pout, u16* __restrict__ Qout, int nnodes) {
  __shared__ __align__(16) u16 s_A[TM * ASTRIDE];
  __shared__ __align__(16) u16 s_W[16384];
  const int t = threadIdx.x;
  const int w = t >> 6, lane = t & 63, quad = lane >> 4, m16 = lane & 15;
  const int tile0 = blockIdx.x * TM;
  const int r_ = t >> 2, qo_ = (t & 3) * 32;
  int node_ = tile0 + r_;
  if (node_ >= nnodes) node_ = nnodes - 1;

  // ---- stage 0: aggr = S@msgW2 + deg*b2m ----
  {
    const int4* src = (const int4*)pw2m;
    int4* dst = (int4*)s_W;
#pragma unroll
    for (int i = 0; i < 8; i++) dst[t + i * 256] = src[t + i * 256];
  }
  {
    const float4* src = (const float4*)(S + (size_t)node_ * HN + qo_);
    u16* dst = s_A + r_ * ASTRIDE + qo_;
#pragma unroll
    for (int i = 0; i < 8; i++) {
      float4 v = src[i];
      ushort4 o;
      o.x = f2bf(v.x); o.y = f2bf(v.y); o.z = f2bf(v.z); o.w = f2bf(v.w);
      *(ushort4*)(dst + i * 4) = o;
    }
  }
  __syncthreads();
  // re-zero S for next layer (reads done)
  {
    float4 z = {0.f, 0.f, 0.f, 0.f};
    float4* zd = (float4*)(S + (size_t)node_ * HN + qo_);
#pragma unroll
    for (int i = 0; i < 8; i++) zd[i] = z;
  }

  f32x4 acc[8];
#pragma unroll
  for (int ct = 0; ct < 8; ct++) acc[ct] = {0.f, 0.f, 0.f, 0.f};
  gemm64(s_A, s_W, w, quad, m16, acc);

  // aggr -> bf16 into wave-private s_A rows
  {
    float b2r[8];
#pragma unroll
    for (int ct = 0; ct < 8; ct++) b2r[ct] = b2m[ct * 16 + m16];
    float degv[4];
#pragma unroll
    for (int j = 0; j < 4; j++) {
      int n = tile0 + w * 16 + quad * 4 + j;
      if (n >= nnodes) n = nnodes - 1;
      degv[j] = (float)deg[n];
    }
#pragma unroll
    for (int ct = 0; ct < 8; ct++)
#pragma unroll
      for (int j = 0; j < 4; j++) {
        int row = w * 16 + quad * 4 + j;
        s_A[row * ASTRIDE + ct * 16 + m16] = f2bf(acc[ct][j] + degv[j] * b2r[ct]);
      }
  }
  __syncthreads();  // all waves done with msgW2
  {
    const int4* src = (const int4*)(pwn + 16384);  // nodeW1b (aggr half)
    int4* dst = (int4*)s_W;
#pragma unroll
    for (int i = 0; i < 8; i++) dst[t + i * 256] = src[t + i * 256];
  }
  __syncthreads();

  // ---- stage 1: acc = aggr@W1b ----
#pragma unroll
  for (int ct = 0; ct < 8; ct++) acc[ct] = {0.f, 0.f, 0.f, 0.f};
  gemm64(s_A, s_W, w, quad, m16, acc);
  __syncthreads();  // all waves done with s_A(aggr) + s_W

  {
    const int4* src = (const int4*)pwn;  // nodeW1a (h half)
    int4* dst = (int4*)s_W;
#pragma unroll
    for (int i = 0; i < 8; i++) dst[t + i * 256] = src[t + i * 256];
  }
  {
    const int4* src = (const int4*)(hbf + (size_t)node_ * HN + qo_);
    int4* dst = (int4*)(s_A + r_ * ASTRIDE + qo_);
#pragma unroll
    for (int i = 0; i < 4; i++) dst[i] = src[i];
  }
  __syncthreads();
  // acc += h@W1a
  gemm64(s_A, s_W, w, quad, m16, acc);
  __syncthreads();

  {
    const int4* src = (const int4*)(pwn + 32768);  // nodeW2
    int4* dst = (int4*)s_W;
#pragma unroll
    for (int i = 0; i < 8; i++) dst[t + i * 256] = src[t + i * 256];
  }
  {
    float bb1[8];
#pragma unroll
    for (int ct = 0; ct < 8; ct++) bb1[ct] = b1[ct * 16 + m16];
#pragma unroll
    for (int ct = 0; ct < 8; ct++)
#pragma unroll
      for (int j = 0; j < 4; j++) {
        int row = w * 16 + quad * 4 + j;
        float xv = acc[ct][j] + bb1[ct];
        s_A[row * ASTRIDE + ct * 16 + m16] = f2bf(silu_f(xv));  // wave-private rows
      }
  }
  __syncthreads();

#pragma unroll
  for (int ct = 0; ct < 8; ct++) acc[ct] = {0.f, 0.f, 0.f, 0.f};
  gemm64(s_A, s_W, w, quad, m16, acc);

  float bb2[8];
#pragma unroll
  for (int ct = 0; ct < 8; ct++) bb2[ct] = b2[ct * 16 + m16];
#pragma unroll
  for (int ct = 0; ct < 8; ct++)
#pragma unroll
    for (int j = 0; j < 4; j++) {
      int row = w * 16 + quad * 4 + j;
      int n = tile0 + row;
      if (n < nnodes) hout[n * HN + ct * 16 + m16] = f2bf(acc[ct][j] + bb2[ct]);
    }

  if (FUSE) {
#pragma unroll
    for (int ct = 0; ct < 8; ct++)
#pragma unroll
      for (int j = 0; j < 4; j++) {
        int row = w * 16 + quad * 4 + j;
        s_A[row * ASTRIDE + ct * 16 + m16] = f2bf(acc[ct][j] + bb2[ct]);  // wave-private
      }
    __syncthreads();
    {
      const int4* src = (const int4*)pw_next;  // msgW1a'
      int4* dst = (int4*)s_W;
#pragma unroll
      for (int i = 0; i < 8; i++) dst[t + i * 256] = src[t + i * 256];
    }
    __syncthreads();
#pragma unroll
    for (int ct = 0; ct < 8; ct++) acc[ct] = {0.f, 0.f, 0.f, 0.f};
    gemm64(s_A, s_W, w, quad, m16, acc);
    {
      float bbn[8];
#pragma unroll
      for (int ct = 0; ct < 8; ct++) bbn[ct] = b1_next[ct * 16 + m16];
#pragma unroll
      for (int ct = 0; ct < 8; ct++)
#pragma unroll
        for (int j = 0; j < 4; j++) {
          int n = tile0 + w * 16 + quad * 4 + j;
          if (n < nnodes) Pout[n * HN + ct * 16 + m16] = f2bf(acc[ct][j] + bbn[ct]);
        }
    }
    __syncthreads();
    {
      const int4* src = (const int4*)(pw_next + 16384);  // msgW1b'
      int4* dst = (int4*)s_W;
#pragma unroll
      for (int i = 0; i < 8; i++) dst[t + i * 256] = src[t + i * 256];
    }
    __syncthreads();
#pragma unroll
    for (int ct = 0; ct < 8; ct++) acc[ct] = {0.f, 0.f, 0.f, 0.f};
    gemm64(s_A, s_W, w, quad, m16, acc);
#pragma unroll
    for (int ct = 0; ct < 8; ct++)
#pragma unroll
      for (int j = 0; j < 4; j++) {
        int n = tile0 + w * 16 + quad * 4 + j;
        if (n < nnodes) Qout[n * HN + ct * 16 + m16] = f2bf(acc[ct][j]);
      }
  }
}

// ---- pool: 469 blocks x 256 thr; thread = (colpair, rowgroup of 16) ----
__global__ __launch_bounds__(256) void pool_kernel(
    const u16* __restrict__ h, const int* __restrict__ batch,
    float* __restrict__ g, int N) {
  __shared__ int s_b[64];
  const int t = threadIdx.x;
  const int n0 = blockIdx.x * 64;
  if (t < 64) {
    int n = n0 + t;
    s_b[t] = (n < N) ? batch[n] : -1;
  }
  __syncthreads();
  const int cp = (t & 63) * 2;
  const int rg = t >> 6;
  int cur = -1;
  float s0 = 0.f, s1 = 0.f;
#pragma unroll 4
  for (int i = 0; i < 16; i++) {
    int r = rg * 16 + i;
    int b = s_b[r];
    if (b < 0) break;  // sorted; -1 only at tail
    if (b != cur) {
      if (cur >= 0) {
        atomicAdd(&g[cur * HN + cp], s0);
        atomicAdd(&g[cur * HN + cp + 1], s1);
      }
      cur = b; s0 = 0.f; s1 = 0.f;
    }
    unsigned v = *(const unsigned*)&h[(size_t)(n0 + r) * HN + cp];
    s0 += bf2f((u16)(v & 0xffffu));
    s1 += bf2f((u16)(v >> 16));
  }
  if (cur >= 0) {
    atomicAdd(&g[cur * HN + cp], s0);
    atomicAdd(&g[cur * HN + cp + 1], s1);
  }
}

// ---- out: one block per graph, split-K halves + shuffle reduce ----
__global__ __launch_bounds__(64) void out_kernel(
    const float* __restrict__ g, const float* __restrict__ w1,
    const float* __restrict__ b1, const float* __restrict__ w2,
    const float* __restrict__ b2, float* __restrict__ out) {
  const int gi = blockIdx.x;
  const int t = threadIdx.x;
  const int c = t & 31, kh = t >> 5;
  float s = 0.f;
  for (int k = kh * 64; k < kh * 64 + 64; k++)
    s += g[gi * HN + k] * w1[k * 32 + c];
  s += __shfl_down(s, 32);
  float r = 0.f;
  if (kh == 0) r = silu_f(s + b1[c]) * w2[c];
  r += __shfl_down(r, 16);
  r += __shfl_down(r, 8);
  r += __shfl_down(r, 4);
  r += __shfl_down(r, 2);
  r += __shfl_down(r, 1);
  if (t == 0) out[gi] = r + b2[0];
}

extern "C" void kernel_launch(void* const* d_in, const int* in_sizes, int n_in,
                              void* d_out, int out_size, void* d_ws, size_t ws_size,
                              hipStream_t stream) {
  const float* x = (const float*)d_in[0];
  const float* pos = (const float*)d_in[1];
  const int* eidx = (const int*)d_in[2];
  const int* batch = (const int*)d_in[3];
  const float* emb_w = (const float*)d_in[4];
  const float* emb_b = (const float*)d_in[5];
  const float* msg_w1 = (const float*)d_in[6];
  const float* msg_b1 = (const float*)d_in[7];
  const float* msg_w2 = (const float*)d_in[8];
  const float* msg_b2 = (const float*)d_in[9];
  const float* node_w1 = (const float*)d_in[10];
  const float* node_b1 = (const float*)d_in[11];
  const float* node_w2 = (const float*)d_in[12];
  const float* node_b2 = (const float*)d_in[13];
  const float* out_w1 = (const float*)d_in[14];
  const float* out_b1 = (const float*)d_in[15];
  const float* out_w2 = (const float*)d_in[16];
  const float* out_b2 = (const float*)d_in[17];
  float* outp = (float*)d_out;

  const int N = 30000, E = 600000, G = 64;
  const size_t NH = (size_t)N * HN;

  u16* hA = (u16*)d_ws;                       // N*128 bf16
  u16* hB = hA + NH;                          // N*128 bf16
  u16* Pp = hB + NH;                          // N*128 bf16
  u16* Qp = Pp + NH;                          // N*128 bf16
  float* S = (float*)(Qp + NH);               // N*128 f32
  int* es = (int*)(S + NH);                   // 3*E (src,tgt,distbits)
  int* deg = es + 3 * (size_t)E;              // N
  int* off = deg + N;                         // N
  int* cursor = off + N;                      // N
  int* bsum = cursor + N;                     // 128
  float* g = (float*)(bsum + 128);            // 64*128 f32
  u16* pw = (u16*)(g + G * HN);               // 4*6*16384 bf16

  const int NB = (N + 255) / 256;
  const int NTB = (N + TM - 1) / TM;

  pack_weights<<<(4 * 6 * 16384 + 255) / 256, 256, 0, stream>>>(msg_w1, msg_w2, node_w1, node_w2, pw);

  // counting sort by target (dist fused into scatter)
  hipMemsetAsync(deg, 0, N * sizeof(int), stream);
  hist_kernel<<<(E + 255) / 256, 256, 0, stream>>>(eidx, deg, E);
  scan1_kernel<<<NB, 256, 0, stream>>>(deg, off, bsum, N);
  scan2_kernel<<<1, 256, 0, stream>>>(bsum, NB);
  scan3_kernel<<<NB, 256, 0, stream>>>(off, bsum, cursor, N);
  scatter_kernel<<<(E + 255) / 256, 256, 0, stream>>>(eidx, pos, cursor, es, E);

  hipMemsetAsync(S, 0, NH * sizeof(float), stream);

  // layer-0: embed + projections fused
  proj_kernel<<<NTB, 256, 0, stream>>>(x, emb_w, emb_b, hA, Pp, Qp, pw, msg_b1, N);

  u16* hcur = hA;
  u16* hnext = hB;
  for (int l = 0; l < 4; l++) {
    const u16* pwl = pw + (size_t)(l * 6) * 16384;
    edge_kernel<<<(E + ECH - 1) / ECH, 256, 0, stream>>>(
        Pp, Qp, S,
        msg_w1 + (size_t)(l * 257 + 256) * 128,  // w1d row (fp32)
        es, E);
    if (l < 3) {
      const u16* pw_next = pw + (size_t)((l + 1) * 6) * 16384;
      node_kernel<true><<<NTB, 256, 0, stream>>>(
          hcur, S, deg, hnext, pwl + 2 * 16384, msg_b2 + l * 128,
          pwl + 3 * 16384, node_b1 + l * 128, node_b2 + l * 128,
          pw_next, msg_b1 + (l + 1) * 128, Pp, Qp, N);
    } else {
      node_kernel<false><<<NTB, 256, 0, stream>>>(
          hcur, S, deg, hnext, pwl + 2 * 16384, msg_b2 + l * 128,
          pwl + 3 * 16384, node_b1 + l * 128, node_b2 + l * 128,
          nullptr, nullptr, nullptr, nullptr, N);
    }
    u16* tmp = hcur; hcur = hnext; hnext = tmp;
  }

  hipMemsetAsync(g, 0, (size_t)G * HN * sizeof(float), stream);
  pool_kernel<<<(N + 63) / 64, 256, 0, stream>>>(hcur, batch, g, N);
  out_kernel<<<G, 64, 0, stream>>>(g, out_w1, out_b1, out_w2, out_b2, outp);
}

// Round 7
// 477.647 us; speedup vs baseline: 2.3137x; 1.2414x over previous
//
#include <hip/hip_runtime.h>

typedef unsigned short u16;
typedef __bf16 bf16x8 __attribute__((ext_vector_type(8)));
typedef float f32x4 __attribute__((ext_vector_type(4)));

#define HN 128
#define TM 64
#define ASTRIDE 136   // 128 + 8 pad (u16), rows 16B-aligned
#define ECH 128       // edges per block in edge_kernel (4 waves x 32)

__device__ __forceinline__ u16 f2bf(float f) {
  union { float f; unsigned u; } v; v.f = f;
  unsigned r = v.u + 0x7fffu + ((v.u >> 16) & 1u);
  return (u16)(r >> 16);
}
__device__ __forceinline__ float bf2f(u16 v) {
  union { unsigned u; float f; } x; x.u = ((unsigned)v) << 16; return x.f;
}
__device__ __forceinline__ float bflo(unsigned v) {
  union { unsigned u; float f; } x; x.u = v << 16; return x.f;
}
__device__ __forceinline__ float bfhi(unsigned v) {
  union { unsigned u; float f; } x; x.u = v & 0xffff0000u; return x.f;
}
__device__ __forceinline__ float silu_f(float x) { return x / (1.f + __expf(-x)); }

// ---- pack weights into MFMA B-fragment layout: P[kg][n][8], kg=k/8 ----
// mats per layer: 0=msgW1a 1=msgW1b 2=msgW2 3=nodeW1a 4=nodeW1b 5=nodeW2
__global__ void pack_weights(const float* __restrict__ msg_w1, const float* __restrict__ msg_w2,
                             const float* __restrict__ node_w1, const float* __restrict__ node_w2,
                             u16* __restrict__ pw) {
  int id = blockIdx.x * 256 + threadIdx.x;
  if (id >= 4 * 6 * 16384) return;
  int l = id / (6 * 16384);
  int rem = id % (6 * 16384);
  int m = rem / 16384;
  int e = rem % 16384;
  int kg = e >> 10;
  int n = (e >> 3) & 127;
  int j = e & 7;
  int k = kg * 8 + j;
  float v = 0.f;
  switch (m) {
    case 0: v = msg_w1[(l * 257 + k) * 128 + n]; break;
    case 1: v = msg_w1[(l * 257 + 128 + k) * 128 + n]; break;
    case 2: v = msg_w2[(l * 128 + k) * 128 + n]; break;
    case 3: v = node_w1[(l * 256 + k) * 128 + n]; break;
    case 4: v = node_w1[(l * 256 + 128 + k) * 128 + n]; break;
    case 5: v = node_w2[(l * 128 + k) * 128 + n]; break;
  }
  pw[id] = f2bf(v);
}

// ---- counting sort of edges by target ----
__global__ void hist_kernel(const int* __restrict__ eidx, int* __restrict__ deg, int E_) {
  int e = blockIdx.x * 256 + threadIdx.x;
  if (e < E_) atomicAdd(&deg[eidx[E_ + e]], 1);
}

__global__ void scan1_kernel(const int* __restrict__ deg, int* __restrict__ off,
                             int* __restrict__ bsum, int n) {
  __shared__ int s[256];
  int t = threadIdx.x;
  int i = blockIdx.x * 256 + t;
  int v = (i < n) ? deg[i] : 0;
  s[t] = v;
  for (int d = 1; d < 256; d <<= 1) {
    __syncthreads();
    int x = (t >= d) ? s[t - d] : 0;
    __syncthreads();
    s[t] += x;
  }
  __syncthreads();
  if (i < n) off[i] = s[t] - v;
  if (t == 255) bsum[blockIdx.x] = s[255];
}

__global__ void scan2_kernel(int* __restrict__ bsum, int nb) {
  __shared__ int s[256];
  int t = threadIdx.x;
  int v = (t < nb) ? bsum[t] : 0;
  s[t] = v;
  for (int d = 1; d < 256; d <<= 1) {
    __syncthreads();
    int x = (t >= d) ? s[t - d] : 0;
    __syncthreads();
    s[t] += x;
  }
  __syncthreads();
  if (t < nb) bsum[t] = s[t] - v;  // exclusive block offsets
}

__global__ void scan3_kernel(int* __restrict__ off, const int* __restrict__ bsum,
                             int* __restrict__ cursor, int n) {
  int i = blockIdx.x * 256 + threadIdx.x;
  if (i < n) {
    int v = off[i] + bsum[blockIdx.x];
    off[i] = v;
    cursor[i] = v;
  }
}

// scatter edges into target-sorted order; dist computed inline
__global__ void scatter_kernel(const int* __restrict__ eidx, const float* __restrict__ pos,
                               int* __restrict__ cursor, int* __restrict__ es, int E_) {
  int e = blockIdx.x * 256 + threadIdx.x;
  if (e >= E_) return;
  int sr = eidx[e], tg = eidx[E_ + e];
  float dx = pos[sr * 3 + 0] - pos[tg * 3 + 0];
  float dy = pos[sr * 3 + 1] - pos[tg * 3 + 1];
  float dz = pos[sr * 3 + 2] - pos[tg * 3 + 2];
  float d = dx * dx + dy * dy + dz * dz;
  int p = atomicAdd(&cursor[tg], 1);
  es[3 * p + 0] = sr;
  es[3 * p + 1] = tg;
  ((float*)es)[3 * p + 2] = d;
}

__device__ __forceinline__ void gemm64(const u16* s_A, const u16* s_W,
                                       int w, int quad, int m16, f32x4 acc[8]) {
#pragma unroll
  for (int ks = 0; ks < 4; ks++) {
    bf16x8 a = *(const bf16x8*)&s_A[(w * 16 + m16) * ASTRIDE + ks * 32 + quad * 8];
#pragma unroll
    for (int ct = 0; ct < 8; ct++) {
      bf16x8 b = *(const bf16x8*)&s_W[(ks * 4 + quad) * 1024 + (ct * 16 + m16) * 8];
      acc[ct] = __builtin_amdgcn_mfma_f32_16x16x32_bf16(a, b, acc[ct], 0, 0, 0);
    }
  }
}

// ---- proj (layer 0, embed fused): h = x*emb_w+emb_b; P = h@W1a + b1, Q = h@W1b ----
__global__ __launch_bounds__(256) void proj_kernel(
    const float* __restrict__ x, const float* __restrict__ emb_w,
    const float* __restrict__ emb_b, u16* __restrict__ hbf,
    u16* __restrict__ Pout, u16* __restrict__ Qout,
    const u16* __restrict__ pw, const float* __restrict__ b1, int nnodes) {
  __shared__ __align__(16) u16 s_A[TM * ASTRIDE];
  __shared__ __align__(16) u16 s_W[16384];
  const int t = threadIdx.x;
  const int w = t >> 6, lane = t & 63, quad = lane >> 4, m16 = lane & 15;
  const int tile0 = blockIdx.x * TM;
  {
    int r = t >> 2, qo = (t & 3) * 32;
    int node = tile0 + r;
    if (node >= nnodes) node = nnodes - 1;
    float xv = x[node];
    u16 hv[32];
#pragma unroll
    for (int i = 0; i < 32; i++) hv[i] = f2bf(xv * emb_w[qo + i] + emb_b[qo + i]);
    u16* dst = s_A + r * ASTRIDE + qo;
#pragma unroll
    for (int i = 0; i < 4; i++) *(int4*)(dst + i * 8) = *(int4*)(hv + i * 8);
    u16* gd = hbf + (size_t)node * HN + qo;
#pragma unroll
    for (int i = 0; i < 4; i++) *(int4*)(gd + i * 8) = *(int4*)(hv + i * 8);
  }
  {
    const int4* src = (const int4*)pw;
    int4* dst = (int4*)s_W;
#pragma unroll
    for (int i = 0; i < 8; i++) dst[t + i * 256] = src[t + i * 256];
  }
  __syncthreads();
  f32x4 acc[8];
#pragma unroll
  for (int ct = 0; ct < 8; ct++) acc[ct] = {0.f, 0.f, 0.f, 0.f};
  gemm64(s_A, s_W, w, quad, m16, acc);
  __syncthreads();
  {
    const int4* src = (const int4*)(pw + 16384);
    int4* dst = (int4*)s_W;
#pragma unroll
    for (int i = 0; i < 8; i++) dst[t + i * 256] = src[t + i * 256];
  }
  float bb[8];
#pragma unroll
  for (int ct = 0; ct < 8; ct++) bb[ct] = b1[ct * 16 + m16];
#pragma unroll
  for (int ct = 0; ct < 8; ct++)
#pragma unroll
    for (int j = 0; j < 4; j++) {
      int n = tile0 + w * 16 + quad * 4 + j;
      if (n < nnodes) Pout[n * HN + ct * 16 + m16] = f2bf(acc[ct][j] + bb[ct]);
    }
  __syncthreads();
#pragma unroll
  for (int ct = 0; ct < 8; ct++) acc[ct] = {0.f, 0.f, 0.f, 0.f};
  gemm64(s_A, s_W, w, quad, m16, acc);
#pragma unroll
  for (int ct = 0; ct < 8; ct++)
#pragma unroll
    for (int j = 0; j < 4; j++) {
      int n = tile0 + w * 16 + quad * 4 + j;
      if (n < nnodes) Qout[n * HN + ct * 16 + m16] = f2bf(acc[ct][j]);
    }
}

// ---- edge kernel v7: 2 cols/thread, 4 waves x 32 edges, 4-deep SW pipeline ----
__device__ __forceinline__ void edge_step(
    int tg, float dd, unsigned qv,
    int& cur, float& p0, float& p1, float& s0, float& s1,
    const u16* __restrict__ P, float* __restrict__ S, int cp,
    float wd0, float wd1, int tprev, int tnext) {
  if (tg != cur) {  // wave-uniform branch
    if (cur >= 0) {
      float* dst = &S[(size_t)cur * HN + cp];
      if (cur == tprev || cur == tnext) {
        atomicAdd(dst, s0);
        atomicAdd(dst + 1, s1);
      } else {
        float2 v = {s0, s1};
        *(float2*)dst = v;
      }
    }
    cur = tg; s0 = 0.f; s1 = 0.f;
    int cg = tg < 0 ? 0 : tg;
    unsigned pv = *(const unsigned*)&P[(size_t)cg * HN + cp];
    p0 = bflo(pv); p1 = bfhi(pv);
  }
  float x0 = p0 + bflo(qv) + dd * wd0;
  float x1 = p1 + bfhi(qv) + dd * wd1;
  s0 += x0 / (1.f + __expf(-x0));
  s1 += x1 / (1.f + __expf(-x1));
}

__global__ __launch_bounds__(256) void edge_kernel(
    const u16* __restrict__ P, const u16* __restrict__ Q,
    float* __restrict__ S, const float* __restrict__ w1d,
    const int* __restrict__ es, int E_) {
  __shared__ int s_src[ECH + 4];
  __shared__ int s_tgt[ECH + 4];
  __shared__ float s_dist[ECH + 4];

  const int t = threadIdx.x;
  const int e0 = blockIdx.x * ECH;
  if (t < ECH) {
    int e = e0 + t;
    if (e < E_) {
      s_src[t] = es[3 * e + 0];
      s_tgt[t] = es[3 * e + 1];
      s_dist[t] = ((const float*)es)[3 * e + 2];
    } else {
      s_src[t] = 0; s_tgt[t] = -1; s_dist[t] = 0.f;
    }
  } else if (t < ECH + 4) {
    s_src[t] = 0; s_tgt[t] = -1; s_dist[t] = 0.f;
  }
  __syncthreads();

  const int lane = t & 63;
  const int w = t >> 6;
  const int cp = lane * 2;
  const int a = w * 32;
  const float2 wdv = *(const float2*)&w1d[cp];
  const float wd0 = wdv.x, wd1 = wdv.y;

  int tprev, tnext;
  if (w == 0) tprev = (e0 > 0) ? es[3 * (e0 - 1) + 1] : -2;
  else tprev = s_tgt[a - 1];
  if (w == 3) tnext = (e0 + ECH < E_) ? es[3 * (e0 + ECH) + 1] : -2;
  else tnext = s_tgt[a + 32];

  // prologue: first 4 edges
  int t0 = s_tgt[a + 0], t1 = s_tgt[a + 1], t2 = s_tgt[a + 2], t3 = s_tgt[a + 3];
  float d0 = s_dist[a + 0], d1 = s_dist[a + 1], d2 = s_dist[a + 2], d3 = s_dist[a + 3];
  unsigned q0 = *(const unsigned*)&Q[(size_t)s_src[a + 0] * HN + cp];
  unsigned q1 = *(const unsigned*)&Q[(size_t)s_src[a + 1] * HN + cp];
  unsigned q2 = *(const unsigned*)&Q[(size_t)s_src[a + 2] * HN + cp];
  unsigned q3 = *(const unsigned*)&Q[(size_t)s_src[a + 3] * HN + cp];

  int cur = -1;
  float s0 = 0.f, s1 = 0.f, p0 = 0.f, p1 = 0.f;

#pragma unroll
  for (int i = a; i < a + 32; i += 4) {
    // prefetch group i+4 (pads make reads safe; results discarded on last group)
    int n0 = s_tgt[i + 4], n1 = s_tgt[i + 5], n2 = s_tgt[i + 6], n3 = s_tgt[i + 7];
    float f0 = s_dist[i + 4], f1 = s_dist[i + 5], f2 = s_dist[i + 6], f3 = s_dist[i + 7];
    unsigned m0 = *(const unsigned*)&Q[(size_t)s_src[i + 4] * HN + cp];
    unsigned m1 = *(const unsigned*)&Q[(size_t)s_src[i + 5] * HN + cp];
    unsigned m2 = *(const unsigned*)&Q[(size_t)s_src[i + 6] * HN + cp];
    unsigned m3 = *(const unsigned*)&Q[(size_t)s_src[i + 7] * HN + cp];

    edge_step(t0, d0, q0, cur, p0, p1, s0, s1, P, S, cp, wd0, wd1, tprev, tnext);
    edge_step(t1, d1, q1, cur, p0, p1, s0, s1, P, S, cp, wd0, wd1, tprev, tnext);
    edge_step(t2, d2, q2, cur, p0, p1, s0, s1, P, S, cp, wd0, wd1, tprev, tnext);
    edge_step(t3, d3, q3, cur, p0, p1, s0, s1, P, S, cp, wd0, wd1, tprev, tnext);

    t0 = n0; t1 = n1; t2 = n2; t3 = n3;
    d0 = f0; d1 = f1; d2 = f2; d3 = f3;
    q0 = m0; q1 = m1; q2 = m2; q3 = m3;
  }

  if (cur >= 0) {
    float* dst = &S[(size_t)cur * HN + cp];
    if (cur == tprev || cur == tnext) {
      atomicAdd(dst, s0);
      atomicAdd(dst + 1, s1);
    } else {
      float2 v = {s0, s1};
      *(float2*)dst = v;
    }
  }
}

// ---- node MLP, aggr fused: aggr = S@msgW2 + deg*b2m (re-zeros S);
// h' = silu([h|aggr]@nodeW1 + b1)@nodeW2 + b2; FUSE: next-layer P/Q ----
template <bool FUSE>
__global__ __launch_bounds__(256) void node_kernel(
    const u16* __restrict__ hbf, float* __restrict__ S, const int* __restrict__ deg,
    u16* __restrict__ hout, const u16* __restrict__ pw2m, const float* __restrict__ b2m,
    const u16* __restrict__ pwn, const float* __restrict__ b1, const float* __restrict__ b2,
    const u16* __restrict__ pw_next, const float* __restrict__ b1_next,
    u16* __restrict__ Pout, u16* __restrict__ Qout, int nnodes) {
  __shared__ __align__(16) u16 s_A[TM * ASTRIDE];
  __shared__ __align__(16) u16 s_W[16384];
  const int t = threadIdx.x;
  const int w = t >> 6, lane = t & 63, quad = lane >> 4, m16 = lane & 15;
  const int tile0 = blockIdx.x * TM;
  const int r_ = t >> 2, qo_ = (t & 3) * 32;
  int node_ = tile0 + r_;
  if (node_ >= nnodes) node_ = nnodes - 1;

  // ---- stage 0: aggr = S@msgW2 + deg*b2m ----
  {
    const int4* src = (const int4*)pw2m;
    int4* dst = (int4*)s_W;
#pragma unroll
    for (int i = 0; i < 8; i++) dst[t + i * 256] = src[t + i * 256];
  }
  {
    const float4* src = (const float4*)(S + (size_t)node_ * HN + qo_);
    u16* dst = s_A + r_ * ASTRIDE + qo_;
#pragma unroll
    for (int i = 0; i < 8; i++) {
      float4 v = src[i];
      ushort4 o;
      o.x = f2bf(v.x); o.y = f2bf(v.y); o.z = f2bf(v.z); o.w = f2bf(v.w);
      *(ushort4*)(dst + i * 4) = o;
    }
  }
  __syncthreads();
  // re-zero S for next layer (reads done)
  {
    float4 z = {0.f, 0.f, 0.f, 0.f};
    float4* zd = (float4*)(S + (size_t)node_ * HN + qo_);
#pragma unroll
    for (int i = 0; i < 8; i++) zd[i] = z;
  }

  f32x4 acc[8];
#pragma unroll
  for (int ct = 0; ct < 8; ct++) acc[ct] = {0.f, 0.f, 0.f, 0.f};
  gemm64(s_A, s_W, w, quad, m16, acc);

  // aggr -> bf16 into wave-private s_A rows
  {
    float b2r[8];
#pragma unroll
    for (int ct = 0; ct < 8; ct++) b2r[ct] = b2m[ct * 16 + m16];
    float degv[4];
#pragma unroll
    for (int j = 0; j < 4; j++) {
      int n = tile0 + w * 16 + quad * 4 + j;
      if (n >= nnodes) n = nnodes - 1;
      degv[j] = (float)deg[n];
    }
#pragma unroll
    for (int ct = 0; ct < 8; ct++)
#pragma unroll
      for (int j = 0; j < 4; j++) {
        int row = w * 16 + quad * 4 + j;
        s_A[row * ASTRIDE + ct * 16 + m16] = f2bf(acc[ct][j] + degv[j] * b2r[ct]);
      }
  }
  __syncthreads();  // all waves done with msgW2
  {
    const int4* src = (const int4*)(pwn + 16384);  // nodeW1b (aggr half)
    int4* dst = (int4*)s_W;
#pragma unroll
    for (int i = 0; i < 8; i++) dst[t + i * 256] = src[t + i * 256];
  }
  __syncthreads();

  // ---- stage 1: acc = aggr@W1b ----
#pragma unroll
  for (int ct = 0; ct < 8; ct++) acc[ct] = {0.f, 0.f, 0.f, 0.f};
  gemm64(s_A, s_W, w, quad, m16, acc);
  __syncthreads();  // all waves done with s_A(aggr) + s_W

  {
    const int4* src = (const int4*)pwn;  // nodeW1a (h half)
    int4* dst = (int4*)s_W;
#pragma unroll
    for (int i = 0; i < 8; i++) dst[t + i * 256] = src[t + i * 256];
  }
  {
    const int4* src = (const int4*)(hbf + (size_t)node_ * HN + qo_);
    int4* dst = (int4*)(s_A + r_ * ASTRIDE + qo_);
#pragma unroll
    for (int i = 0; i < 4; i++) dst[i] = src[i];
  }
  __syncthreads();
  // acc += h@W1a
  gemm64(s_A, s_W, w, quad, m16, acc);
  __syncthreads();

  {
    const int4* src = (const int4*)(pwn + 32768);  // nodeW2
    int4* dst = (int4*)s_W;
#pragma unroll
    for (int i = 0; i < 8; i++) dst[t + i * 256] = src[t + i * 256];
  }
  {
    float bb1[8];
#pragma unroll
    for (int ct = 0; ct < 8; ct++) bb1[ct] = b1[ct * 16 + m16];
#pragma unroll
    for (int ct = 0; ct < 8; ct++)
#pragma unroll
      for (int j = 0; j < 4; j++) {
        int row = w * 16 + quad * 4 + j;
        float xv = acc[ct][j] + bb1[ct];
        s_A[row * ASTRIDE + ct * 16 + m16] = f2bf(silu_f(xv));  // wave-private rows
      }
  }
  __syncthreads();

#pragma unroll
  for (int ct = 0; ct < 8; ct++) acc[ct] = {0.f, 0.f, 0.f, 0.f};
  gemm64(s_A, s_W, w, quad, m16, acc);

  float bb2[8];
#pragma unroll
  for (int ct = 0; ct < 8; ct++) bb2[ct] = b2[ct * 16 + m16];
#pragma unroll
  for (int ct = 0; ct < 8; ct++)
#pragma unroll
    for (int j = 0; j < 4; j++) {
      int row = w * 16 + quad * 4 + j;
      int n = tile0 + row;
      if (n < nnodes) hout[n * HN + ct * 16 + m16] = f2bf(acc[ct][j] + bb2[ct]);
    }

  if (FUSE) {
#pragma unroll
    for (int ct = 0; ct < 8; ct++)
#pragma unroll
      for (int j = 0; j < 4; j++) {
        int row = w * 16 + quad * 4 + j;
        s_A[row * ASTRIDE + ct * 16 + m16] = f2bf(acc[ct][j] + bb2[ct]);  // wave-private
      }
    __syncthreads();
    {
      const int4* src = (const int4*)pw_next;  // msgW1a'
      int4* dst = (int4*)s_W;
#pragma unroll
      for (int i = 0; i < 8; i++) dst[t + i * 256] = src[t + i * 256];
    }
    __syncthreads();
#pragma unroll
    for (int ct = 0; ct < 8; ct++) acc[ct] = {0.f, 0.f, 0.f, 0.f};
    gemm64(s_A, s_W, w, quad, m16, acc);
    {
      float bbn[8];
#pragma unroll
      for (int ct = 0; ct < 8; ct++) bbn[ct] = b1_next[ct * 16 + m16];
#pragma unroll
      for (int ct = 0; ct < 8; ct++)
#pragma unroll
        for (int j = 0; j < 4; j++) {
          int n = tile0 + w * 16 + quad * 4 + j;
          if (n < nnodes) Pout[n * HN + ct * 16 + m16] = f2bf(acc[ct][j] + bbn[ct]);
        }
    }
    __syncthreads();
    {
      const int4* src = (const int4*)(pw_next + 16384);  // msgW1b'
      int4* dst = (int4*)s_W;
#pragma unroll
      for (int i = 0; i < 8; i++) dst[t + i * 256] = src[t + i * 256];
    }
    __syncthreads();
#pragma unroll
    for (int ct = 0; ct < 8; ct++) acc[ct] = {0.f, 0.f, 0.f, 0.f};
    gemm64(s_A, s_W, w, quad, m16, acc);
#pragma unroll
    for (int ct = 0; ct < 8; ct++)
#pragma unroll
      for (int j = 0; j < 4; j++) {
        int n = tile0 + w * 16 + quad * 4 + j;
        if (n < nnodes) Qout[n * HN + ct * 16 + m16] = f2bf(acc[ct][j]);
      }
  }
}

// ---- pool: 469 blocks x 256 thr; thread = (colpair, rowgroup of 16) ----
__global__ __launch_bounds__(256) void pool_kernel(
    const u16* __restrict__ h, const int* __restrict__ batch,
    float* __restrict__ g, int N) {
  __shared__ int s_b[64];
  const int t = threadIdx.x;
  const int n0 = blockIdx.x * 64;
  if (t < 64) {
    int n = n0 + t;
    s_b[t] = (n < N) ? batch[n] : -1;
  }
  __syncthreads();
  const int cp = (t & 63) * 2;
  const int rg = t >> 6;
  int cur = -1;
  float s0 = 0.f, s1 = 0.f;
#pragma unroll 4
  for (int i = 0; i < 16; i++) {
    int r = rg * 16 + i;
    int b = s_b[r];
    if (b < 0) break;  // sorted; -1 only at tail
    if (b != cur) {
      if (cur >= 0) {
        atomicAdd(&g[cur * HN + cp], s0);
        atomicAdd(&g[cur * HN + cp + 1], s1);
      }
      cur = b; s0 = 0.f; s1 = 0.f;
    }
    unsigned v = *(const unsigned*)&h[(size_t)(n0 + r) * HN + cp];
    s0 += bf2f((u16)(v & 0xffffu));
    s1 += bf2f((u16)(v >> 16));
  }
  if (cur >= 0) {
    atomicAdd(&g[cur * HN + cp], s0);
    atomicAdd(&g[cur * HN + cp + 1], s1);
  }
}

// ---- out: one block per graph, split-K halves + shuffle reduce ----
__global__ __launch_bounds__(64) void out_kernel(
    const float* __restrict__ g, const float* __restrict__ w1,
    const float* __restrict__ b1, const float* __restrict__ w2,
    const float* __restrict__ b2, float* __restrict__ out) {
  const int gi = blockIdx.x;
  const int t = threadIdx.x;
  const int c = t & 31, kh = t >> 5;
  float s = 0.f;
  for (int k = kh * 64; k < kh * 64 + 64; k++)
    s += g[gi * HN + k] * w1[k * 32 + c];
  s += __shfl_down(s, 32);
  float r = 0.f;
  if (kh == 0) r = silu_f(s + b1[c]) * w2[c];
  r += __shfl_down(r, 16);
  r += __shfl_down(r, 8);
  r += __shfl_down(r, 4);
  r += __shfl_down(r, 2);
  r += __shfl_down(r, 1);
  if (t == 0) out[gi] = r + b2[0];
}

extern "C" void kernel_launch(void* const* d_in, const int* in_sizes, int n_in,
                              void* d_out, int out_size, void* d_ws, size_t ws_size,
                              hipStream_t stream) {
  const float* x = (const float*)d_in[0];
  const float* pos = (const float*)d_in[1];
  const int* eidx = (const int*)d_in[2];
  const int* batch = (const int*)d_in[3];
  const float* emb_w = (const float*)d_in[4];
  const float* emb_b = (const float*)d_in[5];
  const float* msg_w1 = (const float*)d_in[6];
  const float* msg_b1 = (const float*)d_in[7];
  const float* msg_w2 = (const float*)d_in[8];
  const float* msg_b2 = (const float*)d_in[9];
  const float* node_w1 = (const float*)d_in[10];
  const float* node_b1 = (const float*)d_in[11];
  const float* node_w2 = (const float*)d_in[12];
  const float* node_b2 = (const float*)d_in[13];
  const float* out_w1 = (const float*)d_in[14];
  const float* out_b1 = (const float*)d_in[15];
  const float* out_w2 = (const float*)d_in[16];
  const float* out_b2 = (const float*)d_in[17];
  float* outp = (float*)d_out;

  const int N = 30000, E = 600000, G = 64;
  const size_t NH = (size_t)N * HN;

  u16* hA = (u16*)d_ws;                       // N*128 bf16
  u16* hB = hA + NH;                          // N*128 bf16
  u16* Pp = hB + NH;                          // N*128 bf16
  u16* Qp = Pp + NH;                          // N*128 bf16
  float* S = (float*)(Qp + NH);               // N*128 f32
  int* es = (int*)(S + NH);                   // 3*E (src,tgt,distbits)
  int* deg = es + 3 * (size_t)E;              // N
  int* off = deg + N;                         // N
  int* cursor = off + N;                      // N
  int* bsum = cursor + N;                     // 128
  float* g = (float*)(bsum + 128);            // 64*128 f32
  u16* pw = (u16*)(g + G * HN);               // 4*6*16384 bf16

  const int NB = (N + 255) / 256;
  const int NTB = (N + TM - 1) / TM;

  pack_weights<<<(4 * 6 * 16384 + 255) / 256, 256, 0, stream>>>(msg_w1, msg_w2, node_w1, node_w2, pw);

  // counting sort by target (dist fused into scatter)
  hipMemsetAsync(deg, 0, N * sizeof(int), stream);
  hist_kernel<<<(E + 255) / 256, 256, 0, stream>>>(eidx, deg, E);
  scan1_kernel<<<NB, 256, 0, stream>>>(deg, off, bsum, N);
  scan2_kernel<<<1, 256, 0, stream>>>(bsum, NB);
  scan3_kernel<<<NB, 256, 0, stream>>>(off, bsum, cursor, N);
  scatter_kernel<<<(E + 255) / 256, 256, 0, stream>>>(eidx, pos, cursor, es, E);

  hipMemsetAsync(S, 0, NH * sizeof(float), stream);

  // layer-0: embed + projections fused
  proj_kernel<<<NTB, 256, 0, stream>>>(x, emb_w, emb_b, hA, Pp, Qp, pw, msg_b1, N);

  u16* hcur = hA;
  u16* hnext = hB;
  for (int l = 0; l < 4; l++) {
    const u16* pwl = pw + (size_t)(l * 6) * 16384;
    edge_kernel<<<(E + ECH - 1) / ECH, 256, 0, stream>>>(
        Pp, Qp, S,
        msg_w1 + (size_t)(l * 257 + 256) * 128,  // w1d row (fp32)
        es, E);
    if (l < 3) {
      const u16* pw_next = pw + (size_t)((l + 1) * 6) * 16384;
      node_kernel<true><<<NTB, 256, 0, stream>>>(
          hcur, S, deg, hnext, pwl + 2 * 16384, msg_b2 + l * 128,
          pwl + 3 * 16384, node_b1 + l * 128, node_b2 + l * 128,
          pw_next, msg_b1 + (l + 1) * 128, Pp, Qp, N);
    } else {
      node_kernel<false><<<NTB, 256, 0, stream>>>(
          hcur, S, deg, hnext, pwl + 2 * 16384, msg_b2 + l * 128,
          pwl + 3 * 16384, node_b1 + l * 128, node_b2 + l * 128,
          nullptr, nullptr, nullptr, nullptr, N);
    }
    u16* tmp = hcur; hcur = hnext; hnext = tmp;
  }

  hipMemsetAsync(g, 0, (size_t)G * HN * sizeof(float), stream);
  pool_kernel<<<(N + 63) / 64, 256, 0, stream>>>(hcur, batch, g, N);
  out_kernel<<<G, 64, 0, stream>>>(g, out_w1, out_b1, out_w2, out_b2, outp);
}

// Round 8
// 450.799 us; speedup vs baseline: 2.4515x; 1.0596x over previous
//
#include <hip/hip_runtime.h>

typedef unsigned short u16;
typedef __bf16 bf16x8 __attribute__((ext_vector_type(8)));
typedef float f32x4 __attribute__((ext_vector_type(4)));

#define HN 128
#define TM 64
#define ASTRIDE 136   // 128 + 8 pad (u16), rows 16B-aligned
#define ECH 128       // edges per block in edge_kernel (4 waves x 32)

__device__ __forceinline__ u16 f2bf(float f) {
  union { float f; unsigned u; } v; v.f = f;
  unsigned r = v.u + 0x7fffu + ((v.u >> 16) & 1u);
  return (u16)(r >> 16);
}
__device__ __forceinline__ float bf2f(u16 v) {
  union { unsigned u; float f; } x; x.u = ((unsigned)v) << 16; return x.f;
}
__device__ __forceinline__ float bflo(unsigned v) {
  union { unsigned u; float f; } x; x.u = v << 16; return x.f;
}
__device__ __forceinline__ float bfhi(unsigned v) {
  union { unsigned u; float f; } x; x.u = v & 0xffff0000u; return x.f;
}
// fast silu: x * rcp(1 + exp2(-log2e*x)) — v_exp_f32/v_rcp_f32, ~1 ulp
__device__ __forceinline__ float silu_f(float x) {
  float e = __builtin_amdgcn_exp2f(-1.442695041f * x);
  return x * __builtin_amdgcn_rcpf(1.f + e);
}

// ---- pack weights into MFMA B-fragment layout: P[kg][n][8], kg=k/8 ----
// mats per layer: 0=msgW1a 1=msgW1b 2=msgW2 3=nodeW1a 4=nodeW1b 5=nodeW2
__global__ void pack_weights(const float* __restrict__ msg_w1, const float* __restrict__ msg_w2,
                             const float* __restrict__ node_w1, const float* __restrict__ node_w2,
                             u16* __restrict__ pw) {
  int id = blockIdx.x * 256 + threadIdx.x;
  if (id >= 4 * 6 * 16384) return;
  int l = id / (6 * 16384);
  int rem = id % (6 * 16384);
  int m = rem / 16384;
  int e = rem % 16384;
  int kg = e >> 10;
  int n = (e >> 3) & 127;
  int j = e & 7;
  int k = kg * 8 + j;
  float v = 0.f;
  switch (m) {
    case 0: v = msg_w1[(l * 257 + k) * 128 + n]; break;
    case 1: v = msg_w1[(l * 257 + 128 + k) * 128 + n]; break;
    case 2: v = msg_w2[(l * 128 + k) * 128 + n]; break;
    case 3: v = node_w1[(l * 256 + k) * 128 + n]; break;
    case 4: v = node_w1[(l * 256 + 128 + k) * 128 + n]; break;
    case 5: v = node_w2[(l * 128 + k) * 128 + n]; break;
  }
  pw[id] = f2bf(v);
}

// ---- counting sort of edges by target ----
__global__ void hist_kernel(const int* __restrict__ eidx, int* __restrict__ deg, int E_) {
  int e = blockIdx.x * 256 + threadIdx.x;
  if (e < E_) atomicAdd(&deg[eidx[E_ + e]], 1);
}

__global__ void scan1_kernel(const int* __restrict__ deg, int* __restrict__ off,
                             int* __restrict__ bsum, int n) {
  __shared__ int s[256];
  int t = threadIdx.x;
  int i = blockIdx.x * 256 + t;
  int v = (i < n) ? deg[i] : 0;
  s[t] = v;
  for (int d = 1; d < 256; d <<= 1) {
    __syncthreads();
    int x = (t >= d) ? s[t - d] : 0;
    __syncthreads();
    s[t] += x;
  }
  __syncthreads();
  if (i < n) off[i] = s[t] - v;
  if (t == 255) bsum[blockIdx.x] = s[255];
}

__global__ void scan2_kernel(int* __restrict__ bsum, int nb) {
  __shared__ int s[256];
  int t = threadIdx.x;
  int v = (t < nb) ? bsum[t] : 0;
  s[t] = v;
  for (int d = 1; d < 256; d <<= 1) {
    __syncthreads();
    int x = (t >= d) ? s[t - d] : 0;
    __syncthreads();
    s[t] += x;
  }
  __syncthreads();
  if (t < nb) bsum[t] = s[t] - v;  // exclusive block offsets
}

__global__ void scan3_kernel(int* __restrict__ off, const int* __restrict__ bsum,
                             int* __restrict__ cursor, int n) {
  int i = blockIdx.x * 256 + threadIdx.x;
  if (i < n) {
    int v = off[i] + bsum[blockIdx.x];
    off[i] = v;
    cursor[i] = v;
  }
}

// scatter edges into target-sorted order; dist computed inline
__global__ void scatter_kernel(const int* __restrict__ eidx, const float* __restrict__ pos,
                               int* __restrict__ cursor, int* __restrict__ es, int E_) {
  int e = blockIdx.x * 256 + threadIdx.x;
  if (e >= E_) return;
  int sr = eidx[e], tg = eidx[E_ + e];
  float dx = pos[sr * 3 + 0] - pos[tg * 3 + 0];
  float dy = pos[sr * 3 + 1] - pos[tg * 3 + 1];
  float dz = pos[sr * 3 + 2] - pos[tg * 3 + 2];
  float d = dx * dx + dy * dy + dz * dz;
  int p = atomicAdd(&cursor[tg], 1);
  es[3 * p + 0] = sr;
  es[3 * p + 1] = tg;
  ((float*)es)[3 * p + 2] = d;
}

__device__ __forceinline__ void gemm64(const u16* s_A, const u16* s_W,
                                       int w, int quad, int m16, f32x4 acc[8]) {
#pragma unroll
  for (int ks = 0; ks < 4; ks++) {
    bf16x8 a = *(const bf16x8*)&s_A[(w * 16 + m16) * ASTRIDE + ks * 32 + quad * 8];
#pragma unroll
    for (int ct = 0; ct < 8; ct++) {
      bf16x8 b = *(const bf16x8*)&s_W[(ks * 4 + quad) * 1024 + (ct * 16 + m16) * 8];
      acc[ct] = __builtin_amdgcn_mfma_f32_16x16x32_bf16(a, b, acc[ct], 0, 0, 0);
    }
  }
}

// ---- proj (layer 0, embed fused): h = x*emb_w+emb_b; P = h@W1a + b1, Q = h@W1b ----
__global__ __launch_bounds__(256) void proj_kernel(
    const float* __restrict__ x, const float* __restrict__ emb_w,
    const float* __restrict__ emb_b, u16* __restrict__ hbf,
    u16* __restrict__ Pout, u16* __restrict__ Qout,
    const u16* __restrict__ pw, const float* __restrict__ b1, int nnodes) {
  __shared__ __align__(16) u16 s_A[TM * ASTRIDE];
  __shared__ __align__(16) u16 s_W[16384];
  const int t = threadIdx.x;
  const int w = t >> 6, lane = t & 63, quad = lane >> 4, m16 = lane & 15;
  const int tile0 = blockIdx.x * TM;
  {
    int r = t >> 2, qo = (t & 3) * 32;
    int node = tile0 + r;
    if (node >= nnodes) node = nnodes - 1;
    float xv = x[node];
    u16 hv[32];
#pragma unroll
    for (int i = 0; i < 32; i++) hv[i] = f2bf(xv * emb_w[qo + i] + emb_b[qo + i]);
    u16* dst = s_A + r * ASTRIDE + qo;
#pragma unroll
    for (int i = 0; i < 4; i++) *(int4*)(dst + i * 8) = *(int4*)(hv + i * 8);
    u16* gd = hbf + (size_t)node * HN + qo;
#pragma unroll
    for (int i = 0; i < 4; i++) *(int4*)(gd + i * 8) = *(int4*)(hv + i * 8);
  }
  {
    const int4* src = (const int4*)pw;
    int4* dst = (int4*)s_W;
#pragma unroll
    for (int i = 0; i < 8; i++) dst[t + i * 256] = src[t + i * 256];
  }
  __syncthreads();
  f32x4 acc[8];
#pragma unroll
  for (int ct = 0; ct < 8; ct++) acc[ct] = {0.f, 0.f, 0.f, 0.f};
  gemm64(s_A, s_W, w, quad, m16, acc);
  __syncthreads();
  {
    const int4* src = (const int4*)(pw + 16384);
    int4* dst = (int4*)s_W;
#pragma unroll
    for (int i = 0; i < 8; i++) dst[t + i * 256] = src[t + i * 256];
  }
  float bb[8];
#pragma unroll
  for (int ct = 0; ct < 8; ct++) bb[ct] = b1[ct * 16 + m16];
#pragma unroll
  for (int ct = 0; ct < 8; ct++)
#pragma unroll
    for (int j = 0; j < 4; j++) {
      int n = tile0 + w * 16 + quad * 4 + j;
      if (n < nnodes) Pout[n * HN + ct * 16 + m16] = f2bf(acc[ct][j] + bb[ct]);
    }
  __syncthreads();
#pragma unroll
  for (int ct = 0; ct < 8; ct++) acc[ct] = {0.f, 0.f, 0.f, 0.f};
  gemm64(s_A, s_W, w, quad, m16, acc);
#pragma unroll
  for (int ct = 0; ct < 8; ct++)
#pragma unroll
    for (int j = 0; j < 4; j++) {
      int n = tile0 + w * 16 + quad * 4 + j;
      if (n < nnodes) Qout[n * HN + ct * 16 + m16] = f2bf(acc[ct][j]);
    }
}

// ---- edge kernel: 2 cols/thread, 4 waves x 32 edges, 4-deep SW pipeline ----
__device__ __forceinline__ void edge_step(
    int tg, float dd, unsigned qv,
    int& cur, float& p0, float& p1, float& s0, float& s1,
    const u16* __restrict__ P, float* __restrict__ S, int cp,
    float wd0, float wd1, int tprev, int tnext) {
  if (tg != cur) {  // wave-uniform branch
    if (cur >= 0) {
      float* dst = &S[(size_t)cur * HN + cp];
      if (cur == tprev || cur == tnext) {
        atomicAdd(dst, s0);
        atomicAdd(dst + 1, s1);
      } else {
        float2 v = {s0, s1};
        *(float2*)dst = v;
      }
    }
    cur = tg; s0 = 0.f; s1 = 0.f;
    int cg = tg < 0 ? 0 : tg;
    unsigned pv = *(const unsigned*)&P[(size_t)cg * HN + cp];
    p0 = bflo(pv); p1 = bfhi(pv);
  }
  float x0 = p0 + bflo(qv) + dd * wd0;
  float x1 = p1 + bfhi(qv) + dd * wd1;
  s0 += silu_f(x0);
  s1 += silu_f(x1);
}

__global__ __launch_bounds__(256) void edge_kernel(
    const u16* __restrict__ P, const u16* __restrict__ Q,
    float* __restrict__ S, const float* __restrict__ w1d,
    const int* __restrict__ es, int E_) {
  __shared__ int s_src[ECH + 4];
  __shared__ int s_tgt[ECH + 4];
  __shared__ float s_dist[ECH + 4];

  const int t = threadIdx.x;
  const int e0 = blockIdx.x * ECH;
  if (t < ECH) {
    int e = e0 + t;
    if (e < E_) {
      s_src[t] = es[3 * e + 0];
      s_tgt[t] = es[3 * e + 1];
      s_dist[t] = ((const float*)es)[3 * e + 2];
    } else {
      s_src[t] = 0; s_tgt[t] = -1; s_dist[t] = 0.f;
    }
  } else if (t < ECH + 4) {
    s_src[t] = 0; s_tgt[t] = -1; s_dist[t] = 0.f;
  }
  __syncthreads();

  const int lane = t & 63;
  const int w = t >> 6;
  const int cp = lane * 2;
  const int a = w * 32;
  const float2 wdv = *(const float2*)&w1d[cp];
  const float wd0 = wdv.x, wd1 = wdv.y;

  int tprev, tnext;
  if (w == 0) tprev = (e0 > 0) ? es[3 * (e0 - 1) + 1] : -2;
  else tprev = s_tgt[a - 1];
  if (w == 3) tnext = (e0 + ECH < E_) ? es[3 * (e0 + ECH) + 1] : -2;
  else tnext = s_tgt[a + 32];

  // prologue: first 4 edges
  int t0 = s_tgt[a + 0], t1 = s_tgt[a + 1], t2 = s_tgt[a + 2], t3 = s_tgt[a + 3];
  float d0 = s_dist[a + 0], d1 = s_dist[a + 1], d2 = s_dist[a + 2], d3 = s_dist[a + 3];
  unsigned q0 = *(const unsigned*)&Q[(size_t)s_src[a + 0] * HN + cp];
  unsigned q1 = *(const unsigned*)&Q[(size_t)s_src[a + 1] * HN + cp];
  unsigned q2 = *(const unsigned*)&Q[(size_t)s_src[a + 2] * HN + cp];
  unsigned q3 = *(const unsigned*)&Q[(size_t)s_src[a + 3] * HN + cp];

  int cur = -1;
  float s0 = 0.f, s1 = 0.f, p0 = 0.f, p1 = 0.f;

#pragma unroll
  for (int i = a; i < a + 32; i += 4) {
    // prefetch group i+4 (pads make reads safe; results discarded on last group)
    int n0 = s_tgt[i + 4], n1 = s_tgt[i + 5], n2 = s_tgt[i + 6], n3 = s_tgt[i + 7];
    float f0 = s_dist[i + 4], f1 = s_dist[i + 5], f2 = s_dist[i + 6], f3 = s_dist[i + 7];
    unsigned m0 = *(const unsigned*)&Q[(size_t)s_src[i + 4] * HN + cp];
    unsigned m1 = *(const unsigned*)&Q[(size_t)s_src[i + 5] * HN + cp];
    unsigned m2 = *(const unsigned*)&Q[(size_t)s_src[i + 6] * HN + cp];
    unsigned m3 = *(const unsigned*)&Q[(size_t)s_src[i + 7] * HN + cp];

    edge_step(t0, d0, q0, cur, p0, p1, s0, s1, P, S, cp, wd0, wd1, tprev, tnext);
    edge_step(t1, d1, q1, cur, p0, p1, s0, s1, P, S, cp, wd0, wd1, tprev, tnext);
    edge_step(t2, d2, q2, cur, p0, p1, s0, s1, P, S, cp, wd0, wd1, tprev, tnext);
    edge_step(t3, d3, q3, cur, p0, p1, s0, s1, P, S, cp, wd0, wd1, tprev, tnext);

    t0 = n0; t1 = n1; t2 = n2; t3 = n3;
    d0 = f0; d1 = f1; d2 = f2; d3 = f3;
    q0 = m0; q1 = m1; q2 = m2; q3 = m3;
  }

  if (cur >= 0) {
    float* dst = &S[(size_t)cur * HN + cp];
    if (cur == tprev || cur == tnext) {
      atomicAdd(dst, s0);
      atomicAdd(dst + 1, s1);
    } else {
      float2 v = {s0, s1};
      *(float2*)dst = v;
    }
  }
}

// ---- node MLP, aggr fused: aggr = S@msgW2 + deg*b2m (re-zeros S);
// h' = silu([h|aggr]@nodeW1 + b1)@nodeW2 + b2; FUSE: next-layer P/Q ----
template <bool FUSE>
__global__ __launch_bounds__(256) void node_kernel(
    const u16* __restrict__ hbf, float* __restrict__ S, const int* __restrict__ deg,
    u16* __restrict__ hout, const u16* __restrict__ pw2m, const float* __restrict__ b2m,
    const u16* __restrict__ pwn, const float* __restrict__ b1, const float* __restrict__ b2,
    const u16* __restrict__ pw_next, const float* __restrict__ b1_next,
    u16* __restrict__ Pout, u16* __restrict__ Qout, int nnodes) {
  __shared__ __align__(16) u16 s_A[TM * ASTRIDE];
  __shared__ __align__(16) u16 s_W[16384];
  const int t = threadIdx.x;
  const int w = t >> 6, lane = t & 63, quad = lane >> 4, m16 = lane & 15;
  const int tile0 = blockIdx.x * TM;
  const int r_ = t >> 2, qo_ = (t & 3) * 32;
  int node_ = tile0 + r_;
  if (node_ >= nnodes) node_ = nnodes - 1;

  // ---- stage 0: aggr = S@msgW2 + deg*b2m ----
  {
    const int4* src = (const int4*)pw2m;
    int4* dst = (int4*)s_W;
#pragma unroll
    for (int i = 0; i < 8; i++) dst[t + i * 256] = src[t + i * 256];
  }
  {
    const float4* src = (const float4*)(S + (size_t)node_ * HN + qo_);
    u16* dst = s_A + r_ * ASTRIDE + qo_;
#pragma unroll
    for (int i = 0; i < 8; i++) {
      float4 v = src[i];
      ushort4 o;
      o.x = f2bf(v.x); o.y = f2bf(v.y); o.z = f2bf(v.z); o.w = f2bf(v.w);
      *(ushort4*)(dst + i * 4) = o;
    }
  }
  __syncthreads();
  // re-zero S for next layer (reads done)
  {
    float4 z = {0.f, 0.f, 0.f, 0.f};
    float4* zd = (float4*)(S + (size_t)node_ * HN + qo_);
#pragma unroll
    for (int i = 0; i < 8; i++) zd[i] = z;
  }

  f32x4 acc[8];
#pragma unroll
  for (int ct = 0; ct < 8; ct++) acc[ct] = {0.f, 0.f, 0.f, 0.f};
  gemm64(s_A, s_W, w, quad, m16, acc);

  // aggr -> bf16 into wave-private s_A rows
  {
    float b2r[8];
#pragma unroll
    for (int ct = 0; ct < 8; ct++) b2r[ct] = b2m[ct * 16 + m16];
    float degv[4];
#pragma unroll
    for (int j = 0; j < 4; j++) {
      int n = tile0 + w * 16 + quad * 4 + j;
      if (n >= nnodes) n = nnodes - 1;
      degv[j] = (float)deg[n];
    }
#pragma unroll
    for (int ct = 0; ct < 8; ct++)
#pragma unroll
      for (int j = 0; j < 4; j++) {
        int row = w * 16 + quad * 4 + j;
        s_A[row * ASTRIDE + ct * 16 + m16] = f2bf(acc[ct][j] + degv[j] * b2r[ct]);
      }
  }
  __syncthreads();  // all waves done with msgW2
  {
    const int4* src = (const int4*)(pwn + 16384);  // nodeW1b (aggr half)
    int4* dst = (int4*)s_W;
#pragma unroll
    for (int i = 0; i < 8; i++) dst[t + i * 256] = src[t + i * 256];
  }
  __syncthreads();

  // ---- stage 1: acc = aggr@W1b ----
#pragma unroll
  for (int ct = 0; ct < 8; ct++) acc[ct] = {0.f, 0.f, 0.f, 0.f};
  gemm64(s_A, s_W, w, quad, m16, acc);
  __syncthreads();  // all waves done with s_A(aggr) + s_W

  {
    const int4* src = (const int4*)pwn;  // nodeW1a (h half)
    int4* dst = (int4*)s_W;
#pragma unroll
    for (int i = 0; i < 8; i++) dst[t + i * 256] = src[t + i * 256];
  }
  {
    const int4* src = (const int4*)(hbf + (size_t)node_ * HN + qo_);
    int4* dst = (int4*)(s_A + r_ * ASTRIDE + qo_);
#pragma unroll
    for (int i = 0; i < 4; i++) dst[i] = src[i];
  }
  __syncthreads();
  // acc += h@W1a
  gemm64(s_A, s_W, w, quad, m16, acc);
  __syncthreads();

  {
    const int4* src = (const int4*)(pwn + 32768);  // nodeW2
    int4* dst = (int4*)s_W;
#pragma unroll
    for (int i = 0; i < 8; i++) dst[t + i * 256] = src[t + i * 256];
  }
  {
    float bb1[8];
#pragma unroll
    for (int ct = 0; ct < 8; ct++) bb1[ct] = b1[ct * 16 + m16];
#pragma unroll
    for (int ct = 0; ct < 8; ct++)
#pragma unroll
      for (int j = 0; j < 4; j++) {
        int row = w * 16 + quad * 4 + j;
        float xv = acc[ct][j] + bb1[ct];
        s_A[row * ASTRIDE + ct * 16 + m16] = f2bf(silu_f(xv));  // wave-private rows
      }
  }
  __syncthreads();

#pragma unroll
  for (int ct = 0; ct < 8; ct++) acc[ct] = {0.f, 0.f, 0.f, 0.f};
  gemm64(s_A, s_W, w, quad, m16, acc);

  float bb2[8];
#pragma unroll
  for (int ct = 0; ct < 8; ct++) bb2[ct] = b2[ct * 16 + m16];
#pragma unroll
  for (int ct = 0; ct < 8; ct++)
#pragma unroll
    for (int j = 0; j < 4; j++) {
      int row = w * 16 + quad * 4 + j;
      int n = tile0 + row;
      if (n < nnodes) hout[n * HN + ct * 16 + m16] = f2bf(acc[ct][j] + bb2[ct]);
    }

  if (FUSE) {
#pragma unroll
    for (int ct = 0; ct < 8; ct++)
#pragma unroll
      for (int j = 0; j < 4; j++) {
        int row = w * 16 + quad * 4 + j;
        s_A[row * ASTRIDE + ct * 16 + m16] = f2bf(acc[ct][j] + bb2[ct]);  // wave-private
      }
    __syncthreads();
    {
      const int4* src = (const int4*)pw_next;  // msgW1a'
      int4* dst = (int4*)s_W;
#pragma unroll
      for (int i = 0; i < 8; i++) dst[t + i * 256] = src[t + i * 256];
    }
    __syncthreads();
#pragma unroll
    for (int ct = 0; ct < 8; ct++) acc[ct] = {0.f, 0.f, 0.f, 0.f};
    gemm64(s_A, s_W, w, quad, m16, acc);
    {
      float bbn[8];
#pragma unroll
      for (int ct = 0; ct < 8; ct++) bbn[ct] = b1_next[ct * 16 + m16];
#pragma unroll
      for (int ct = 0; ct < 8; ct++)
#pragma unroll
        for (int j = 0; j < 4; j++) {
          int n = tile0 + w * 16 + quad * 4 + j;
          if (n < nnodes) Pout[n * HN + ct * 16 + m16] = f2bf(acc[ct][j] + bbn[ct]);
        }
    }
    __syncthreads();
    {
      const int4* src = (const int4*)(pw_next + 16384);  // msgW1b'
      int4* dst = (int4*)s_W;
#pragma unroll
      for (int i = 0; i < 8; i++) dst[t + i * 256] = src[t + i * 256];
    }
    __syncthreads();
#pragma unroll
    for (int ct = 0; ct < 8; ct++) acc[ct] = {0.f, 0.f, 0.f, 0.f};
    gemm64(s_A, s_W, w, quad, m16, acc);
#pragma unroll
    for (int ct = 0; ct < 8; ct++)
#pragma unroll
      for (int j = 0; j < 4; j++) {
        int n = tile0 + w * 16 + quad * 4 + j;
        if (n < nnodes) Qout[n * HN + ct * 16 + m16] = f2bf(acc[ct][j]);
      }
  }
}

// ---- pool: 469 blocks x 256 thr; thread = (colpair, rowgroup of 16) ----
__global__ __launch_bounds__(256) void pool_kernel(
    const u16* __restrict__ h, const int* __restrict__ batch,
    float* __restrict__ g, int N) {
  __shared__ int s_b[64];
  const int t = threadIdx.x;
  const int n0 = blockIdx.x * 64;
  if (t < 64) {
    int n = n0 + t;
    s_b[t] = (n < N) ? batch[n] : -1;
  }
  __syncthreads();
  const int cp = (t & 63) * 2;
  const int rg = t >> 6;
  int cur = -1;
  float s0 = 0.f, s1 = 0.f;
#pragma unroll 4
  for (int i = 0; i < 16; i++) {
    int r = rg * 16 + i;
    int b = s_b[r];
    if (b < 0) break;  // sorted; -1 only at tail
    if (b != cur) {
      if (cur >= 0) {
        atomicAdd(&g[cur * HN + cp], s0);
        atomicAdd(&g[cur * HN + cp + 1], s1);
      }
      cur = b; s0 = 0.f; s1 = 0.f;
    }
    unsigned v = *(const unsigned*)&h[(size_t)(n0 + r) * HN + cp];
    s0 += bf2f((u16)(v & 0xffffu));
    s1 += bf2f((u16)(v >> 16));
  }
  if (cur >= 0) {
    atomicAdd(&g[cur * HN + cp], s0);
    atomicAdd(&g[cur * HN + cp + 1], s1);
  }
}

// ---- out: one block per graph, split-K halves + shuffle reduce ----
__global__ __launch_bounds__(64) void out_kernel(
    const float* __restrict__ g, const float* __restrict__ w1,
    const float* __restrict__ b1, const float* __restrict__ w2,
    const float* __restrict__ b2, float* __restrict__ out) {
  const int gi = blockIdx.x;
  const int t = threadIdx.x;
  const int c = t & 31, kh = t >> 5;
  float s = 0.f;
  for (int k = kh * 64; k < kh * 64 + 64; k++)
    s += g[gi * HN + k] * w1[k * 32 + c];
  s += __shfl_down(s, 32);
  float r = 0.f;
  if (kh == 0) r = silu_f(s + b1[c]) * w2[c];
  r += __shfl_down(r, 16);
  r += __shfl_down(r, 8);
  r += __shfl_down(r, 4);
  r += __shfl_down(r, 2);
  r += __shfl_down(r, 1);
  if (t == 0) out[gi] = r + b2[0];
}

extern "C" void kernel_launch(void* const* d_in, const int* in_sizes, int n_in,
                              void* d_out, int out_size, void* d_ws, size_t ws_size,
                              hipStream_t stream) {
  const float* x = (const float*)d_in[0];
  const float* pos = (const float*)d_in[1];
  const int* eidx = (const int*)d_in[2];
  const int* batch = (const int*)d_in[3];
  const float* emb_w = (const float*)d_in[4];
  const float* emb_b = (const float*)d_in[5];
  const float* msg_w1 = (const float*)d_in[6];
  const float* msg_b1 = (const float*)d_in[7];
  const float* msg_w2 = (const float*)d_in[8];
  const float* msg_b2 = (const float*)d_in[9];
  const float* node_w1 = (const float*)d_in[10];
  const float* node_b1 = (const float*)d_in[11];
  const float* node_w2 = (const float*)d_in[12];
  const float* node_b2 = (const float*)d_in[13];
  const float* out_w1 = (const float*)d_in[14];
  const float* out_b1 = (const float*)d_in[15];
  const float* out_w2 = (const float*)d_in[16];
  const float* out_b2 = (const float*)d_in[17];
  float* outp = (float*)d_out;

  const int N = 30000, E = 600000, G = 64;
  const size_t NH = (size_t)N * HN;

  u16* hA = (u16*)d_ws;                       // N*128 bf16
  u16* hB = hA + NH;                          // N*128 bf16
  u16* Pp = hB + NH;                          // N*128 bf16
  u16* Qp = Pp + NH;                          // N*128 bf16
  float* S = (float*)(Qp + NH);               // N*128 f32
  int* es = (int*)(S + NH);                   // 3*E (src,tgt,distbits)
  int* deg = es + 3 * (size_t)E;              // N
  int* off = deg + N;                         // N
  int* cursor = off + N;                      // N
  int* bsum = cursor + N;                     // 128
  float* g = (float*)(bsum + 128);            // 64*128 f32
  u16* pw = (u16*)(g + G * HN);               // 4*6*16384 bf16

  const int NB = (N + 255) / 256;
  const int NTB = (N + TM - 1) / TM;

  pack_weights<<<(4 * 6 * 16384 + 255) / 256, 256, 0, stream>>>(msg_w1, msg_w2, node_w1, node_w2, pw);

  // counting sort by target (dist fused into scatter)
  hipMemsetAsync(deg, 0, N * sizeof(int), stream);
  hist_kernel<<<(E + 255) / 256, 256, 0, stream>>>(eidx, deg, E);
  scan1_kernel<<<NB, 256, 0, stream>>>(deg, off, bsum, N);
  scan2_kernel<<<1, 256, 0, stream>>>(bsum, NB);
  scan3_kernel<<<NB, 256, 0, stream>>>(off, bsum, cursor, N);
  scatter_kernel<<<(E + 255) / 256, 256, 0, stream>>>(eidx, pos, cursor, es, E);

  hipMemsetAsync(S, 0, NH * sizeof(float), stream);

  // layer-0: embed + projections fused
  proj_kernel<<<NTB, 256, 0, stream>>>(x, emb_w, emb_b, hA, Pp, Qp, pw, msg_b1, N);

  u16* hcur = hA;
  u16* hnext = hB;
  for (int l = 0; l < 4; l++) {
    const u16* pwl = pw + (size_t)(l * 6) * 16384;
    edge_kernel<<<(E + ECH - 1) / ECH, 256, 0, stream>>>(
        Pp, Qp, S,
        msg_w1 + (size_t)(l * 257 + 256) * 128,  // w1d row (fp32)
        es, E);
    if (l < 3) {
      const u16* pw_next = pw + (size_t)((l + 1) * 6) * 16384;
      node_kernel<true><<<NTB, 256, 0, stream>>>(
          hcur, S, deg, hnext, pwl + 2 * 16384, msg_b2 + l * 128,
          pwl + 3 * 16384, node_b1 + l * 128, node_b2 + l * 128,
          pw_next, msg_b1 + (l + 1) * 128, Pp, Qp, N);
    } else {
      node_kernel<false><<<NTB, 256, 0, stream>>>(
          hcur, S, deg, hnext, pwl + 2 * 16384, msg_b2 + l * 128,
          pwl + 3 * 16384, node_b1 + l * 128, node_b2 + l * 128,
          nullptr, nullptr, nullptr, nullptr, N);
    }
    u16* tmp = hcur; hcur = hnext; hnext = tmp;
  }

  hipMemsetAsync(g, 0, (size_t)G * HN * sizeof(float), stream);
  pool_kernel<<<(N + 63) / 64, 256, 0, stream>>>(hcur, batch, g, N);
  out_kernel<<<G, 64, 0, stream>>>(g, out_w1, out_b1, out_w2, out_b2, outp);
}

// Round 9
// 428.596 us; speedup vs baseline: 2.5785x; 1.0518x over previous
//
#include <hip/hip_runtime.h>

typedef unsigned short u16;
typedef __bf16 bf16x8 __attribute__((ext_vector_type(8)));
typedef float f32x4 __attribute__((ext_vector_type(4)));

#define HN 128
#define TM 64
#define ASTRIDE 136   // 128 + 8 pad (u16), rows 16B-aligned
#define ECH 256       // edges per block in edge_kernel (4 waves x 64)

__device__ __forceinline__ u16 f2bf(float f) {
  union { float f; unsigned u; } v; v.f = f;
  unsigned r = v.u + 0x7fffu + ((v.u >> 16) & 1u);
  return (u16)(r >> 16);
}
__device__ __forceinline__ float bf2f(u16 v) {
  union { unsigned u; float f; } x; x.u = ((unsigned)v) << 16; return x.f;
}
__device__ __forceinline__ float bflo(unsigned v) {
  union { unsigned u; float f; } x; x.u = v << 16; return x.f;
}
__device__ __forceinline__ float bfhi(unsigned v) {
  union { unsigned u; float f; } x; x.u = v & 0xffff0000u; return x.f;
}
// fast silu: x * rcp(1 + exp2(-log2e*x)) — v_exp_f32/v_rcp_f32, ~1 ulp
__device__ __forceinline__ float silu_f(float x) {
  float e = __builtin_amdgcn_exp2f(-1.442695041f * x);
  return x * __builtin_amdgcn_rcpf(1.f + e);
}

// ---- pack weights into MFMA B-fragment layout: P[kg][n][8], kg=k/8 ----
// mats per layer: 0=msgW1a 1=msgW1b 2=msgW2 3=nodeW1a 4=nodeW1b 5=nodeW2
__global__ void pack_weights(const float* __restrict__ msg_w1, const float* __restrict__ msg_w2,
                             const float* __restrict__ node_w1, const float* __restrict__ node_w2,
                             u16* __restrict__ pw) {
  int id = blockIdx.x * 256 + threadIdx.x;
  if (id >= 4 * 6 * 16384) return;
  int l = id / (6 * 16384);
  int rem = id % (6 * 16384);
  int m = rem / 16384;
  int e = rem % 16384;
  int kg = e >> 10;
  int n = (e >> 3) & 127;
  int j = e & 7;
  int k = kg * 8 + j;
  float v = 0.f;
  switch (m) {
    case 0: v = msg_w1[(l * 257 + k) * 128 + n]; break;
    case 1: v = msg_w1[(l * 257 + 128 + k) * 128 + n]; break;
    case 2: v = msg_w2[(l * 128 + k) * 128 + n]; break;
    case 3: v = node_w1[(l * 256 + k) * 128 + n]; break;
    case 4: v = node_w1[(l * 256 + 128 + k) * 128 + n]; break;
    case 5: v = node_w2[(l * 128 + k) * 128 + n]; break;
  }
  pw[id] = f2bf(v);
}

__device__ __forceinline__ void gemm64(const u16* s_A, const u16* s_W,
                                       int w, int quad, int m16, f32x4 acc[8]) {
#pragma unroll
  for (int ks = 0; ks < 4; ks++) {
    bf16x8 a = *(const bf16x8*)&s_A[(w * 16 + m16) * ASTRIDE + ks * 32 + quad * 8];
#pragma unroll
    for (int ct = 0; ct < 8; ct++) {
      bf16x8 b = *(const bf16x8*)&s_W[(ks * 4 + quad) * 1024 + (ct * 16 + m16) * 8];
      acc[ct] = __builtin_amdgcn_mfma_f32_16x16x32_bf16(a, b, acc[ct], 0, 0, 0);
    }
  }
}

// ---- fold: Wc = msgW2 @ nodeW1b (bf16, B-frag packed), vc = msg_b2 @ nodeW1b ----
// 8 blocks: l = b>>1, row-half = b&1. Uses pw mat4 (nodeW1b packed) as B.
__global__ __launch_bounds__(256) void fold_kernel(
    const float* __restrict__ msg_w2, const float* __restrict__ node_w1,
    const float* __restrict__ msg_b2, const u16* __restrict__ pw,
    u16* __restrict__ pwc, float* __restrict__ vc) {
  __shared__ __align__(16) u16 s_A[TM * ASTRIDE];
  __shared__ __align__(16) u16 s_W[16384];
  const int t = threadIdx.x;
  const int w = t >> 6, lane = t & 63, quad = lane >> 4, m16 = lane & 15;
  const int b = blockIdx.x, l = b >> 1, half = b & 1;
  const int tile0 = half * 64;

  {
    int r = t >> 2, qo = (t & 3) * 32;
    const float4* src = (const float4*)(msg_w2 + (size_t)(l * 128 + tile0 + r) * 128 + qo);
    u16* dst = s_A + r * ASTRIDE + qo;
#pragma unroll
    for (int i = 0; i < 8; i++) {
      float4 v = src[i];
      ushort4 o;
      o.x = f2bf(v.x); o.y = f2bf(v.y); o.z = f2bf(v.z); o.w = f2bf(v.w);
      *(ushort4*)(dst + i * 4) = o;
    }
  }
  {
    const int4* src = (const int4*)(pw + (size_t)(l * 6 + 4) * 16384);
    int4* dst = (int4*)s_W;
#pragma unroll
    for (int i = 0; i < 8; i++) dst[t + i * 256] = src[t + i * 256];
  }
  __syncthreads();
  f32x4 acc[8];
#pragma unroll
  for (int ct = 0; ct < 8; ct++) acc[ct] = {0.f, 0.f, 0.f, 0.f};
  gemm64(s_A, s_W, w, quad, m16, acc);
#pragma unroll
  for (int ct = 0; ct < 8; ct++)
#pragma unroll
    for (int j = 0; j < 4; j++) {
      int k = tile0 + w * 16 + quad * 4 + j;
      int n = ct * 16 + m16;
      pwc[(size_t)l * 16384 + (k >> 3) * 1024 + n * 8 + (k & 7)] = f2bf(acc[ct][j]);
    }
  if (half == 0 && t < 128) {
    float s = 0.f;
    for (int np = 0; np < 128; np++)
      s += msg_b2[l * 128 + np] * node_w1[(size_t)(l * 256 + 128 + np) * 128 + t];
    vc[l * 128 + t] = s;
  }
}

// ---- counting sort of edges by target ----
__global__ void hist_kernel(const int* __restrict__ eidx, int* __restrict__ deg, int E_) {
  int e = blockIdx.x * 256 + threadIdx.x;
  if (e < E_) atomicAdd(&deg[eidx[E_ + e]], 1);
}

__global__ void scan1_kernel(const int* __restrict__ deg, int* __restrict__ off,
                             int* __restrict__ bsum, int n) {
  __shared__ int s[256];
  int t = threadIdx.x;
  int i = blockIdx.x * 256 + t;
  int v = (i < n) ? deg[i] : 0;
  s[t] = v;
  for (int d = 1; d < 256; d <<= 1) {
    __syncthreads();
    int x = (t >= d) ? s[t - d] : 0;
    __syncthreads();
    s[t] += x;
  }
  __syncthreads();
  if (i < n) off[i] = s[t] - v;
  if (t == 255) bsum[blockIdx.x] = s[255];
}

__global__ void scan2_kernel(int* __restrict__ bsum, int nb) {
  __shared__ int s[256];
  int t = threadIdx.x;
  int v = (t < nb) ? bsum[t] : 0;
  s[t] = v;
  for (int d = 1; d < 256; d <<= 1) {
    __syncthreads();
    int x = (t >= d) ? s[t - d] : 0;
    __syncthreads();
    s[t] += x;
  }
  __syncthreads();
  if (t < nb) bsum[t] = s[t] - v;  // exclusive block offsets
}

__global__ void scan3_kernel(int* __restrict__ off, const int* __restrict__ bsum,
                             int* __restrict__ cursor, int n) {
  int i = blockIdx.x * 256 + threadIdx.x;
  if (i < n) {
    int v = off[i] + bsum[blockIdx.x];
    off[i] = v;
    cursor[i] = v;
  }
}

// scatter edges into target-sorted order; dist computed inline
__global__ void scatter_kernel(const int* __restrict__ eidx, const float* __restrict__ pos,
                               int* __restrict__ cursor, int* __restrict__ es, int E_) {
  int e = blockIdx.x * 256 + threadIdx.x;
  if (e >= E_) return;
  int sr = eidx[e], tg = eidx[E_ + e];
  float dx = pos[sr * 3 + 0] - pos[tg * 3 + 0];
  float dy = pos[sr * 3 + 1] - pos[tg * 3 + 1];
  float dz = pos[sr * 3 + 2] - pos[tg * 3 + 2];
  float d = dx * dx + dy * dy + dz * dz;
  int p = atomicAdd(&cursor[tg], 1);
  es[3 * p + 0] = sr;
  es[3 * p + 1] = tg;
  ((float*)es)[3 * p + 2] = d;
}

// ---- proj (layer 0, embed fused): h = x*emb_w+emb_b; P = h@W1a + b1, Q = h@W1b ----
__global__ __launch_bounds__(256) void proj_kernel(
    const float* __restrict__ x, const float* __restrict__ emb_w,
    const float* __restrict__ emb_b, u16* __restrict__ hbf,
    u16* __restrict__ Pout, u16* __restrict__ Qout,
    const u16* __restrict__ pw, const float* __restrict__ b1, int nnodes) {
  __shared__ __align__(16) u16 s_A[TM * ASTRIDE];
  __shared__ __align__(16) u16 s_W[16384];
  const int t = threadIdx.x;
  const int w = t >> 6, lane = t & 63, quad = lane >> 4, m16 = lane & 15;
  const int tile0 = blockIdx.x * TM;
  {
    int r = t >> 2, qo = (t & 3) * 32;
    int node = tile0 + r;
    if (node >= nnodes) node = nnodes - 1;
    float xv = x[node];
    u16 hv[32];
#pragma unroll
    for (int i = 0; i < 32; i++) hv[i] = f2bf(xv * emb_w[qo + i] + emb_b[qo + i]);
    u16* dst = s_A + r * ASTRIDE + qo;
#pragma unroll
    for (int i = 0; i < 4; i++) *(int4*)(dst + i * 8) = *(int4*)(hv + i * 8);
    u16* gd = hbf + (size_t)node * HN + qo;
#pragma unroll
    for (int i = 0; i < 4; i++) *(int4*)(gd + i * 8) = *(int4*)(hv + i * 8);
  }
  {
    const int4* src = (const int4*)pw;
    int4* dst = (int4*)s_W;
#pragma unroll
    for (int i = 0; i < 8; i++) dst[t + i * 256] = src[t + i * 256];
  }
  __syncthreads();
  f32x4 acc[8];
#pragma unroll
  for (int ct = 0; ct < 8; ct++) acc[ct] = {0.f, 0.f, 0.f, 0.f};
  gemm64(s_A, s_W, w, quad, m16, acc);
  __syncthreads();
  {
    const int4* src = (const int4*)(pw + 16384);
    int4* dst = (int4*)s_W;
#pragma unroll
    for (int i = 0; i < 8; i++) dst[t + i * 256] = src[t + i * 256];
  }
  float bb[8];
#pragma unroll
  for (int ct = 0; ct < 8; ct++) bb[ct] = b1[ct * 16 + m16];
#pragma unroll
  for (int ct = 0; ct < 8; ct++)
#pragma unroll
    for (int j = 0; j < 4; j++) {
      int n = tile0 + w * 16 + quad * 4 + j;
      if (n < nnodes) Pout[n * HN + ct * 16 + m16] = f2bf(acc[ct][j] + bb[ct]);
    }
  __syncthreads();
#pragma unroll
  for (int ct = 0; ct < 8; ct++) acc[ct] = {0.f, 0.f, 0.f, 0.f};
  gemm64(s_A, s_W, w, quad, m16, acc);
#pragma unroll
  for (int ct = 0; ct < 8; ct++)
#pragma unroll
    for (int j = 0; j < 4; j++) {
      int n = tile0 + w * 16 + quad * 4 + j;
      if (n < nnodes) Qout[n * HN + ct * 16 + m16] = f2bf(acc[ct][j]);
    }
}

// ---- edge kernel: 2 cols/thread, 4 waves x 64 edges, 4-deep SW pipeline ----
__device__ __forceinline__ void edge_step(
    int tg, float dd, unsigned qv,
    int& cur, float& p0, float& p1, float& s0, float& s1,
    const u16* __restrict__ P, float* __restrict__ S, int cp,
    float wd0, float wd1, int tprev, int tnext) {
  if (tg != cur) {  // wave-uniform branch
    if (cur >= 0) {
      float* dst = &S[(size_t)cur * HN + cp];
      if (cur == tprev || cur == tnext) {
        atomicAdd(dst, s0);
        atomicAdd(dst + 1, s1);
      } else {
        float2 v = {s0, s1};
        *(float2*)dst = v;
      }
    }
    cur = tg; s0 = 0.f; s1 = 0.f;
    int cg = tg < 0 ? 0 : tg;
    unsigned pv = *(const unsigned*)&P[(size_t)cg * HN + cp];
    p0 = bflo(pv); p1 = bfhi(pv);
  }
  float x0 = p0 + bflo(qv) + dd * wd0;
  float x1 = p1 + bfhi(qv) + dd * wd1;
  s0 += silu_f(x0);
  s1 += silu_f(x1);
}

__global__ __launch_bounds__(256) void edge_kernel(
    const u16* __restrict__ P, const u16* __restrict__ Q,
    float* __restrict__ S, const float* __restrict__ w1d,
    const int* __restrict__ es, int E_) {
  __shared__ int s_src[ECH + 4];
  __shared__ int s_tgt[ECH + 4];
  __shared__ float s_dist[ECH + 4];

  const int t = threadIdx.x;
  const int e0 = blockIdx.x * ECH;
  {
    int e = e0 + t;
    if (e < E_) {
      s_src[t] = es[3 * e + 0];
      s_tgt[t] = es[3 * e + 1];
      s_dist[t] = ((const float*)es)[3 * e + 2];
    } else {
      s_src[t] = 0; s_tgt[t] = -1; s_dist[t] = 0.f;
    }
    if (t < 4) { s_src[ECH + t] = 0; s_tgt[ECH + t] = -1; s_dist[ECH + t] = 0.f; }
  }
  __syncthreads();

  const int lane = t & 63;
  const int w = t >> 6;
  const int cp = lane * 2;
  const int a = w * 64;
  const float2 wdv = *(const float2*)&w1d[cp];
  const float wd0 = wdv.x, wd1 = wdv.y;

  int tprev, tnext;
  if (w == 0) tprev = (e0 > 0) ? es[3 * (e0 - 1) + 1] : -2;
  else tprev = s_tgt[a - 1];
  if (w == 3) tnext = (e0 + ECH < E_) ? es[3 * (e0 + ECH) + 1] : -2;
  else tnext = s_tgt[a + 64];

  // prologue: first 4 edges
  int t0 = s_tgt[a + 0], t1 = s_tgt[a + 1], t2 = s_tgt[a + 2], t3 = s_tgt[a + 3];
  float d0 = s_dist[a + 0], d1 = s_dist[a + 1], d2 = s_dist[a + 2], d3 = s_dist[a + 3];
  unsigned q0 = *(const unsigned*)&Q[(size_t)s_src[a + 0] * HN + cp];
  unsigned q1 = *(const unsigned*)&Q[(size_t)s_src[a + 1] * HN + cp];
  unsigned q2 = *(const unsigned*)&Q[(size_t)s_src[a + 2] * HN + cp];
  unsigned q3 = *(const unsigned*)&Q[(size_t)s_src[a + 3] * HN + cp];

  int cur = -1;
  float s0 = 0.f, s1 = 0.f, p0 = 0.f, p1 = 0.f;

#pragma unroll 4
  for (int i = a; i < a + 64; i += 4) {
    // prefetch group i+4 (pads make reads safe; results discarded on last group)
    int n0 = s_tgt[i + 4], n1 = s_tgt[i + 5], n2 = s_tgt[i + 6], n3 = s_tgt[i + 7];
    float f0 = s_dist[i + 4], f1 = s_dist[i + 5], f2 = s_dist[i + 6], f3 = s_dist[i + 7];
    unsigned m0 = *(const unsigned*)&Q[(size_t)s_src[i + 4] * HN + cp];
    unsigned m1 = *(const unsigned*)&Q[(size_t)s_src[i + 5] * HN + cp];
    unsigned m2 = *(const unsigned*)&Q[(size_t)s_src[i + 6] * HN + cp];
    unsigned m3 = *(const unsigned*)&Q[(size_t)s_src[i + 7] * HN + cp];

    edge_step(t0, d0, q0, cur, p0, p1, s0, s1, P, S, cp, wd0, wd1, tprev, tnext);
    edge_step(t1, d1, q1, cur, p0, p1, s0, s1, P, S, cp, wd0, wd1, tprev, tnext);
    edge_step(t2, d2, q2, cur, p0, p1, s0, s1, P, S, cp, wd0, wd1, tprev, tnext);
    edge_step(t3, d3, q3, cur, p0, p1, s0, s1, P, S, cp, wd0, wd1, tprev, tnext);

    t0 = n0; t1 = n1; t2 = n2; t3 = n3;
    d0 = f0; d1 = f1; d2 = f2; d3 = f3;
    q0 = m0; q1 = m1; q2 = m2; q3 = m3;
  }

  if (cur >= 0) {
    float* dst = &S[(size_t)cur * HN + cp];
    if (cur == tprev || cur == tnext) {
      atomicAdd(dst, s0);
      atomicAdd(dst + 1, s1);
    } else {
      float2 v = {s0, s1};
      *(float2*)dst = v;
    }
  }
}

// ---- node MLP with folded aggr: pre = S@Wc + h@W1a + deg*vc + b1;
// h' = silu(pre)@nodeW2 + b2; FUSE: next-layer P/Q ----
template <bool FUSE>
__global__ __launch_bounds__(256) void node_kernel(
    const u16* __restrict__ hbf, float* __restrict__ S, const int* __restrict__ deg,
    u16* __restrict__ hout, const u16* __restrict__ pwc, const float* __restrict__ vc,
    const u16* __restrict__ pwn, const float* __restrict__ b1, const float* __restrict__ b2,
    const u16* __restrict__ pw_next, const float* __restrict__ b1_next,
    u16* __restrict__ Pout, u16* __restrict__ Qout, int nnodes) {
  __shared__ __align__(16) u16 s_A[TM * ASTRIDE];
  __shared__ __align__(16) u16 s_W[16384];
  const int t = threadIdx.x;
  const int w = t >> 6, lane = t & 63, quad = lane >> 4, m16 = lane & 15;
  const int tile0 = blockIdx.x * TM;
  const int r_ = t >> 2, qo_ = (t & 3) * 32;
  int node_ = tile0 + r_;
  if (node_ >= nnodes) node_ = nnodes - 1;

  // ---- stage A: acc = S@Wc ----
  {
    const int4* src = (const int4*)pwc;
    int4* dst = (int4*)s_W;
#pragma unroll
    for (int i = 0; i < 8; i++) dst[t + i * 256] = src[t + i * 256];
  }
  {
    const float4* src = (const float4*)(S + (size_t)node_ * HN + qo_);
    u16* dst = s_A + r_ * ASTRIDE + qo_;  // wave-private rows
#pragma unroll
    for (int i = 0; i < 8; i++) {
      float4 v = src[i];
      ushort4 o;
      o.x = f2bf(v.x); o.y = f2bf(v.y); o.z = f2bf(v.z); o.w = f2bf(v.w);
      *(ushort4*)(dst + i * 4) = o;
    }
    // re-zero S for next layer (own reads done)
    float4 z = {0.f, 0.f, 0.f, 0.f};
    float4* zd = (float4*)(S + (size_t)node_ * HN + qo_);
#pragma unroll
    for (int i = 0; i < 8; i++) zd[i] = z;
  }
  __syncthreads();

  f32x4 acc[8];
#pragma unroll
  for (int ct = 0; ct < 8; ct++) acc[ct] = {0.f, 0.f, 0.f, 0.f};
  gemm64(s_A, s_W, w, quad, m16, acc);
  __syncthreads();  // s_W reads done

  // ---- stage B: acc += h@W1a ----
  {
    const int4* src = (const int4*)pwn;  // nodeW1a
    int4* dst = (int4*)s_W;
#pragma unroll
    for (int i = 0; i < 8; i++) dst[t + i * 256] = src[t + i * 256];
  }
  {
    const int4* src = (const int4*)(hbf + (size_t)node_ * HN + qo_);
    int4* dst = (int4*)(s_A + r_ * ASTRIDE + qo_);  // wave-private rows
#pragma unroll
    for (int i = 0; i < 4; i++) dst[i] = src[i];
  }
  __syncthreads();
  gemm64(s_A, s_W, w, quad, m16, acc);
  __syncthreads();

  // ---- stage C: silu(acc + deg*vc + b1) -> s_A; acc2 = hidden@W2n ----
  {
    const int4* src = (const int4*)(pwn + 32768);  // nodeW2
    int4* dst = (int4*)s_W;
#pragma unroll
    for (int i = 0; i < 8; i++) dst[t + i * 256] = src[t + i * 256];
  }
  {
    float bb1[8], vcr[8];
#pragma unroll
    for (int ct = 0; ct < 8; ct++) {
      bb1[ct] = b1[ct * 16 + m16];
      vcr[ct] = vc[ct * 16 + m16];
    }
    float degv[4];
#pragma unroll
    for (int j = 0; j < 4; j++) {
      int n = tile0 + w * 16 + quad * 4 + j;
      if (n >= nnodes) n = nnodes - 1;
      degv[j] = (float)deg[n];
    }
#pragma unroll
    for (int ct = 0; ct < 8; ct++)
#pragma unroll
      for (int j = 0; j < 4; j++) {
        int row = w * 16 + quad * 4 + j;
        float xv = acc[ct][j] + bb1[ct] + degv[j] * vcr[ct];
        s_A[row * ASTRIDE + ct * 16 + m16] = f2bf(silu_f(xv));  // wave-private rows
      }
  }
  __syncthreads();

#pragma unroll
  for (int ct = 0; ct < 8; ct++) acc[ct] = {0.f, 0.f, 0.f, 0.f};
  gemm64(s_A, s_W, w, quad, m16, acc);

  float bb2[8];
#pragma unroll
  for (int ct = 0; ct < 8; ct++) bb2[ct] = b2[ct * 16 + m16];
#pragma unroll
  for (int ct = 0; ct < 8; ct++)
#pragma unroll
    for (int j = 0; j < 4; j++) {
      int row = w * 16 + quad * 4 + j;
      int n = tile0 + row;
      if (n < nnodes) hout[n * HN + ct * 16 + m16] = f2bf(acc[ct][j] + bb2[ct]);
    }

  if (FUSE) {
#pragma unroll
    for (int ct = 0; ct < 8; ct++)
#pragma unroll
      for (int j = 0; j < 4; j++) {
        int row = w * 16 + quad * 4 + j;
        s_A[row * ASTRIDE + ct * 16 + m16] = f2bf(acc[ct][j] + bb2[ct]);  // wave-private
      }
    __syncthreads();  // stage-C s_W reads done before overwrite
    {
      const int4* src = (const int4*)pw_next;  // msgW1a'
      int4* dst = (int4*)s_W;
#pragma unroll
      for (int i = 0; i < 8; i++) dst[t + i * 256] = src[t + i * 256];
    }
    __syncthreads();
#pragma unroll
    for (int ct = 0; ct < 8; ct++) acc[ct] = {0.f, 0.f, 0.f, 0.f};
    gemm64(s_A, s_W, w, quad, m16, acc);
    {
      float bbn[8];
#pragma unroll
      for (int ct = 0; ct < 8; ct++) bbn[ct] = b1_next[ct * 16 + m16];
#pragma unroll
      for (int ct = 0; ct < 8; ct++)
#pragma unroll
        for (int j = 0; j < 4; j++) {
          int n = tile0 + w * 16 + quad * 4 + j;
          if (n < nnodes) Pout[n * HN + ct * 16 + m16] = f2bf(acc[ct][j] + bbn[ct]);
        }
    }
    __syncthreads();
    {
      const int4* src = (const int4*)(pw_next + 16384);  // msgW1b'
      int4* dst = (int4*)s_W;
#pragma unroll
      for (int i = 0; i < 8; i++) dst[t + i * 256] = src[t + i * 256];
    }
    __syncthreads();
#pragma unroll
    for (int ct = 0; ct < 8; ct++) acc[ct] = {0.f, 0.f, 0.f, 0.f};
    gemm64(s_A, s_W, w, quad, m16, acc);
#pragma unroll
    for (int ct = 0; ct < 8; ct++)
#pragma unroll
      for (int j = 0; j < 4; j++) {
        int n = tile0 + w * 16 + quad * 4 + j;
        if (n < nnodes) Qout[n * HN + ct * 16 + m16] = f2bf(acc[ct][j]);
      }
  }
}

// ---- pool: 469 blocks x 256 thr; thread = (colpair, rowgroup of 16) ----
__global__ __launch_bounds__(256) void pool_kernel(
    const u16* __restrict__ h, const int* __restrict__ batch,
    float* __restrict__ g, int N) {
  __shared__ int s_b[64];
  const int t = threadIdx.x;
  const int n0 = blockIdx.x * 64;
  if (t < 64) {
    int n = n0 + t;
    s_b[t] = (n < N) ? batch[n] : -1;
  }
  __syncthreads();
  const int cp = (t & 63) * 2;
  const int rg = t >> 6;
  int cur = -1;
  float s0 = 0.f, s1 = 0.f;
#pragma unroll 4
  for (int i = 0; i < 16; i++) {
    int r = rg * 16 + i;
    int b = s_b[r];
    if (b < 0) break;  // sorted; -1 only at tail
    if (b != cur) {
      if (cur >= 0) {
        atomicAdd(&g[cur * HN + cp], s0);
        atomicAdd(&g[cur * HN + cp + 1], s1);
      }
      cur = b; s0 = 0.f; s1 = 0.f;
    }
    unsigned v = *(const unsigned*)&h[(size_t)(n0 + r) * HN + cp];
    s0 += bf2f((u16)(v & 0xffffu));
    s1 += bf2f((u16)(v >> 16));
  }
  if (cur >= 0) {
    atomicAdd(&g[cur * HN + cp], s0);
    atomicAdd(&g[cur * HN + cp + 1], s1);
  }
}

// ---- out: one block per graph, split-K halves + shuffle reduce ----
__global__ __launch_bounds__(64) void out_kernel(
    const float* __restrict__ g, const float* __restrict__ w1,
    const float* __restrict__ b1, const float* __restrict__ w2,
    const float* __restrict__ b2, float* __restrict__ out) {
  const int gi = blockIdx.x;
  const int t = threadIdx.x;
  const int c = t & 31, kh = t >> 5;
  float s = 0.f;
  for (int k = kh * 64; k < kh * 64 + 64; k++)
    s += g[gi * HN + k] * w1[k * 32 + c];
  s += __shfl_down(s, 32);
  float r = 0.f;
  if (kh == 0) r = silu_f(s + b1[c]) * w2[c];
  r += __shfl_down(r, 16);
  r += __shfl_down(r, 8);
  r += __shfl_down(r, 4);
  r += __shfl_down(r, 2);
  r += __shfl_down(r, 1);
  if (t == 0) out[gi] = r + b2[0];
}

extern "C" void kernel_launch(void* const* d_in, const int* in_sizes, int n_in,
                              void* d_out, int out_size, void* d_ws, size_t ws_size,
                              hipStream_t stream) {
  const float* x = (const float*)d_in[0];
  const float* pos = (const float*)d_in[1];
  const int* eidx = (const int*)d_in[2];
  const int* batch = (const int*)d_in[3];
  const float* emb_w = (const float*)d_in[4];
  const float* emb_b = (const float*)d_in[5];
  const float* msg_w1 = (const float*)d_in[6];
  const float* msg_b1 = (const float*)d_in[7];
  const float* msg_w2 = (const float*)d_in[8];
  const float* msg_b2 = (const float*)d_in[9];
  const float* node_w1 = (const float*)d_in[10];
  const float* node_b1 = (const float*)d_in[11];
  const float* node_w2 = (const float*)d_in[12];
  const float* node_b2 = (const float*)d_in[13];
  const float* out_w1 = (const float*)d_in[14];
  const float* out_b1 = (const float*)d_in[15];
  const float* out_w2 = (const float*)d_in[16];
  const float* out_b2 = (const float*)d_in[17];
  float* outp = (float*)d_out;

  const int N = 30000, E = 600000, G = 64;
  const size_t NH = (size_t)N * HN;

  u16* hA = (u16*)d_ws;                       // N*128 bf16
  u16* hB = hA + NH;                          // N*128 bf16
  u16* Pp = hB + NH;                          // N*128 bf16
  u16* Qp = Pp + NH;                          // N*128 bf16
  float* S = (float*)(Qp + NH);               // N*128 f32
  int* es = (int*)(S + NH);                   // 3*E (src,tgt,distbits)
  int* deg = es + 3 * (size_t)E;              // N
  int* off = deg + N;                         // N
  int* cursor = off + N;                      // N
  int* bsum = cursor + N;                     // 128
  float* g = (float*)(bsum + 128);            // 64*128 f32
  u16* pw = (u16*)(g + G * HN);               // 4*6*16384 bf16
  u16* pwc = pw + (size_t)4 * 6 * 16384;      // 4*16384 bf16 (folded Wc)
  float* vcb = (float*)(pwc + (size_t)4 * 16384);  // 4*128 f32

  const int NB = (N + 255) / 256;
  const int NTB = (N + TM - 1) / TM;

  pack_weights<<<(4 * 6 * 16384 + 255) / 256, 256, 0, stream>>>(msg_w1, msg_w2, node_w1, node_w2, pw);
  fold_kernel<<<8, 256, 0, stream>>>(msg_w2, node_w1, msg_b2, pw, pwc, vcb);

  // counting sort by target (dist fused into scatter)
  hipMemsetAsync(deg, 0, N * sizeof(int), stream);
  hist_kernel<<<(E + 255) / 256, 256, 0, stream>>>(eidx, deg, E);
  scan1_kernel<<<NB, 256, 0, stream>>>(deg, off, bsum, N);
  scan2_kernel<<<1, 256, 0, stream>>>(bsum, NB);
  scan3_kernel<<<NB, 256, 0, stream>>>(off, bsum, cursor, N);
  scatter_kernel<<<(E + 255) / 256, 256, 0, stream>>>(eidx, pos, cursor, es, E);

  hipMemsetAsync(S, 0, NH * sizeof(float), stream);

  // layer-0: embed + projections fused
  proj_kernel<<<NTB, 256, 0, stream>>>(x, emb_w, emb_b, hA, Pp, Qp, pw, msg_b1, N);

  u16* hcur = hA;
  u16* hnext = hB;
  for (int l = 0; l < 4; l++) {
    const u16* pwl = pw + (size_t)(l * 6) * 16384;
    edge_kernel<<<(E + ECH - 1) / ECH, 256, 0, stream>>>(
        Pp, Qp, S,
        msg_w1 + (size_t)(l * 257 + 256) * 128,  // w1d row (fp32)
        es, E);
    if (l < 3) {
      const u16* pw_next = pw + (size_t)((l + 1) * 6) * 16384;
      node_kernel<true><<<NTB, 256, 0, stream>>>(
          hcur, S, deg, hnext, pwc + (size_t)l * 16384, vcb + l * 128,
          pwl + 3 * 16384, node_b1 + l * 128, node_b2 + l * 128,
          pw_next, msg_b1 + (l + 1) * 128, Pp, Qp, N);
    } else {
      node_kernel<false><<<NTB, 256, 0, stream>>>(
          hcur, S, deg, hnext, pwc + (size_t)l * 16384, vcb + l * 128,
          pwl + 3 * 16384, node_b1 + l * 128, node_b2 + l * 128,
          nullptr, nullptr, nullptr, nullptr, N);
    }
    u16* tmp = hcur; hcur = hnext; hnext = tmp;
  }

  hipMemsetAsync(g, 0, (size_t)G * HN * sizeof(float), stream);
  pool_kernel<<<(N + 63) / 64, 256, 0, stream>>>(hcur, batch, g, N);
  out_kernel<<<G, 64, 0, stream>>>(g, out_w1, out_b1, out_w2, out_b2, outp);
}